// Round 1
// 634.099 us; speedup vs baseline: 1.1141x; 1.1141x over previous
//
#include <hip/hip_runtime.h>
#include <hip/hip_fp16.h>

// Problem constants
#define NN 100000
#define EE 500000
#define F_NODE 128
#define F_EDGE 32
#define HEADS 4
#define CC 64
#define HC 256
#define OUTD 32
#define NEG_SLOPE 0.2f
#define BN_SCALE 0.9999950000374997f   // 1/sqrt(1+1e-5)
#define NB_SCAN 391                    // ceil(NN/256)

using half8 = __attribute__((ext_vector_type(8))) _Float16;
using f32x4 = __attribute__((ext_vector_type(4))) float;

// ---------------------------------------------------------------------------
// MFMA GEMM: C[m][n] = sum_k A[m][k] * Wt[n][k]  (A fp16 MxK row-major,
// Wt fp16 NxK row-major = W transposed, C fp16).
// Block = 4 waves, BM=32 rows; wave w owns cols [w*NOUT/4, (w+1)*NOUT/4).
// Fragments: lane holds 8 contiguous k (16B) at row/col (lane&15),
// k-offset (lane>>4)*8  [m97-verified layout]. C/D: col=lane&15,
// row=(lane>>4)*4+reg [m89-verified].
// MODE 1: + bias[col], ReLU.
// ---------------------------------------------------------------------------
template<int K, int NOUT, int MODE>
__global__ __launch_bounds__(256) void mgemm(const __half* __restrict__ A,
                                             const __half* __restrict__ Wt,
                                             const float* __restrict__ bias,
                                             __half* __restrict__ C) {
    constexpr int WN = NOUT / 4;       // cols per wave
    constexpr int NT = WN / 16;        // 16-col tiles per wave
    constexpr int KSTEPS = K / 32;
    const int wave = threadIdx.x >> 6, lane = threadIdx.x & 63;
    const int m0 = blockIdx.x * 32;
    const int n0 = wave * WN;
    const int lrow = lane & 15;
    const int kofs = (lane >> 4) * 8;

    f32x4 acc[2][NT] = {};

    const __half* Ap = A + (size_t)(m0 + lrow) * K + kofs;
    const __half* Bp = Wt + (size_t)(n0 + lrow) * K + kofs;

    for (int ks = 0; ks < KSTEPS; ++ks) {
        half8 a0 = *(const half8*)(Ap + ks * 32);
        half8 a1 = *(const half8*)(Ap + (size_t)16 * K + ks * 32);
        half8 b[NT];
#pragma unroll
        for (int nt = 0; nt < NT; ++nt)
            b[nt] = *(const half8*)(Bp + (size_t)nt * 16 * K + ks * 32);
#pragma unroll
        for (int nt = 0; nt < NT; ++nt) {
            acc[0][nt] = __builtin_amdgcn_mfma_f32_16x16x32_f16(a0, b[nt], acc[0][nt], 0, 0, 0);
            acc[1][nt] = __builtin_amdgcn_mfma_f32_16x16x32_f16(a1, b[nt], acc[1][nt], 0, 0, 0);
        }
    }

    const int crow = (lane >> 4) * 4;
#pragma unroll
    for (int mt = 0; mt < 2; ++mt) {
#pragma unroll
        for (int nt = 0; nt < NT; ++nt) {
            const int col = n0 + nt * 16 + lrow;
            float bcol = (MODE == 1) ? bias[col] : 0.f;
#pragma unroll
            for (int r = 0; r < 4; ++r) {
                float v = acc[mt][nt][r];
                if constexpr (MODE == 1) v = fmaxf(v + bcol, 0.f);
                C[(size_t)(m0 + mt * 16 + crow + r) * NOUT + col] = __float2half(v);
            }
        }
    }
}

// ---------------------------------------------------------------------------
// Prep kernels: transpose-convert weights to fp16 NxK, cast x to fp16.
// ---------------------------------------------------------------------------
__global__ __launch_bounds__(256) void wt_conv(const float* __restrict__ W,
                                               __half* __restrict__ Wt,
                                               int K, int N) {
    int idx = blockIdx.x * 256 + threadIdx.x;   // over N*K, output-contiguous
    if (idx >= K * N) return;
    int n = idx / K, k = idx % K;
    Wt[idx] = __float2half(W[k * N + n]);
}

// Wt_final[n][k]: n<32 -> W1[k][n] (W1s), n>=32 -> W1[256+k][n-32] (W1d)
__global__ __launch_bounds__(256) void wt_final(const float* __restrict__ W1,
                                                __half* __restrict__ Wt) {
    int idx = blockIdx.x * 256 + threadIdx.x;   // over 64*256
    if (idx >= 64 * 256) return;
    int n = idx >> 8, k = idx & 255;
    float v = (n < 32) ? W1[k * 32 + n] : W1[(256 + k) * 32 + (n - 32)];
    Wt[idx] = __float2half(v);
}

__global__ __launch_bounds__(256) void cvt_x(const float* __restrict__ x,
                                             __half* __restrict__ x16) {
    int i = blockIdx.x * 256 + threadIdx.x;     // over NN*F_NODE/4
    float4 v = ((const float4*)x)[i];
    __half2* o = (__half2*)x16 + (size_t)i * 2;
    o[0] = __floats2half2_rn(v.x, v.y);
    o[1] = __floats2half2_rn(v.z, v.w);
}

// ---------------------------------------------------------------------------
// CSR build: deg-count, two-level exclusive scan, scatter.
// ---------------------------------------------------------------------------
__global__ __launch_bounds__(256) void csr_count(const int* __restrict__ dst,
                                                 int* __restrict__ deg,
                                                 int* __restrict__ pos) {
    int e = blockIdx.x * 256 + threadIdx.x;
    if (e >= EE) return;
    pos[e] = atomicAdd(deg + dst[e], 1);
}

__device__ __forceinline__ int wave_incl_scan(int v, int lane) {
#pragma unroll
    for (int off = 1; off < 64; off <<= 1) {
        int t = __shfl_up(v, off, 64);
        if (lane >= off) v += t;
    }
    return v;
}

__global__ __launch_bounds__(256) void scan1(const int* __restrict__ deg,
                                             int* __restrict__ rowptr,
                                             int* __restrict__ bsum) {
    int tid = threadIdx.x, n = blockIdx.x * 256 + tid;
    int lane = tid & 63, wave = tid >> 6;
    int d = (n < NN) ? deg[n] : 0;
    int v = wave_incl_scan(d, lane);
    __shared__ int ws[4];
    if (lane == 63) ws[wave] = v;
    __syncthreads();
    int woff = 0;
    for (int w = 0; w < wave; ++w) woff += ws[w];
    int incl = v + woff;
    if (n < NN) rowptr[n] = incl - d;
    if (tid == 255) bsum[blockIdx.x] = incl;
}

__global__ __launch_bounds__(512) void scan2(const int* __restrict__ bsum,
                                             int* __restrict__ boff) {
    int t = threadIdx.x;
    int lane = t & 63, wave = t >> 6;
    int d = (t < NB_SCAN) ? bsum[t] : 0;
    int v = wave_incl_scan(d, lane);
    __shared__ int ws[8];
    if (lane == 63) ws[wave] = v;
    __syncthreads();
    int woff = 0;
    for (int w = 0; w < wave; ++w) woff += ws[w];
    if (t < NB_SCAN) boff[t] = v + woff - d;
}

__global__ __launch_bounds__(256) void scan3(int* __restrict__ rowptr,
                                             const int* __restrict__ boff) {
    int n = blockIdx.x * 256 + threadIdx.x;
    if (n == 0) rowptr[NN] = EE;
    if (n < NN) rowptr[n] += boff[blockIdx.x];
}

__global__ __launch_bounds__(256) void csr_scatter(const int* __restrict__ src,
                                                   const int* __restrict__ dst,
                                                   const int* __restrict__ rowptr,
                                                   const int* __restrict__ pos,
                                                   int* __restrict__ perm,
                                                   int* __restrict__ srcs) {
    int e = blockIdx.x * 256 + threadIdx.x;
    if (e >= EE) return;
    int p = rowptr[dst[e]] + pos[e];
    perm[e] = p;
    srcs[p] = src[e];
}

// ---------------------------------------------------------------------------
// a_s[n][h] = sum_c xh[n][h*64+c]*att_s[h*64+c]; same for a_d.
// ---------------------------------------------------------------------------
__global__ __launch_bounds__(256) void att_score(const __half* __restrict__ xh,
                                                 const float* __restrict__ as_,
                                                 const float* __restrict__ ad_,
                                                 float* __restrict__ a_s,
                                                 float* __restrict__ a_d) {
    const int lane = threadIdx.x & 63, wave = threadIdx.x >> 6;
    const int n = blockIdx.x * 4 + wave;
    const int c0 = lane * 4;

    float ws0 = as_[c0], ws1 = as_[c0 + 1], ws2 = as_[c0 + 2], ws3 = as_[c0 + 3];
    float wd0 = ad_[c0], wd1 = ad_[c0 + 1], wd2 = ad_[c0 + 2], wd3 = ad_[c0 + 3];

    const __half2* p = (const __half2*)(xh + (size_t)n * HC);
    __half2 v0 = p[lane * 2], v1 = p[lane * 2 + 1];
    float x0 = __low2float(v0), x1 = __high2float(v0);
    float x2 = __low2float(v1), x3 = __high2float(v1);

    float ss = x0 * ws0 + x1 * ws1 + x2 * ws2 + x3 * ws3;
    float dd = x0 * wd0 + x1 * wd1 + x2 * wd2 + x3 * wd3;
#pragma unroll
    for (int m = 8; m >= 1; m >>= 1) {
        ss += __shfl_xor(ss, m, 64);
        dd += __shfl_xor(dd, m, 64);
    }
    if ((lane & 15) == 0) {
        a_s[n * HEADS + (lane >> 4)] = ss;
        a_d[n * HEADS + (lane >> 4)] = dd;
    }
}

// ---------------------------------------------------------------------------
// Per (edge, head): ex = exp(leaky_relu(a_s[src]+a_d[dst])), written to the
// CSR-sorted slot (softmax shift-invariant; logits tiny -> no segment_max).
// ---------------------------------------------------------------------------
__global__ __launch_bounds__(256) void edge_score(const int* __restrict__ src,
                                                  const int* __restrict__ dst,
                                                  const int* __restrict__ perm,
                                                  const float* __restrict__ a_s,
                                                  const float* __restrict__ a_d,
                                                  float* __restrict__ exs) {
    int idx = blockIdx.x * 256 + threadIdx.x;
    if (idx >= EE * HEADS) return;
    int e = idx >> 2, h = idx & 3;
    int s = src[e], d = dst[e];
    float v = a_s[s * HEADS + h] + a_d[d * HEADS + h];
    v = (v > 0.f) ? v : v * NEG_SLOPE;
    exs[perm[e] * HEADS + h] = __expf(v);
}

// ---------------------------------------------------------------------------
// Gather-aggregate + fused BN/ReLU/residual. One wave per dst node, no atomics.
// ---------------------------------------------------------------------------
__global__ __launch_bounds__(256) void gather_agg(const int* __restrict__ rowptr,
                                                  const int* __restrict__ srcs,
                                                  const float* __restrict__ exs,
                                                  const __half* __restrict__ xh,
                                                  const float* __restrict__ bg,
                                                  const float* __restrict__ g,
                                                  const float* __restrict__ be,
                                                  __half* __restrict__ h,
                                                  int residual) {
    const int n = blockIdx.x * 4 + (threadIdx.x >> 6);
    const int lane = threadIdx.x & 63;
    if (n >= NN) return;
    const int hd = lane >> 4;
    const int c0 = lane * 4;

    const int start = rowptr[n], end = rowptr[n + 1];
    float a0 = 0.f, a1 = 0.f, a2 = 0.f, a3 = 0.f, den = 0.f;
    for (int i = start; i < end; ++i) {
        float ex = exs[i * HEADS + hd];
        int s = srcs[i];
        union { float2 f2; __half2 h2[2]; } u;
        u.f2 = *(const float2*)(xh + (size_t)s * HC + c0);
        a0 += ex * __low2float(u.h2[0]);
        a1 += ex * __high2float(u.h2[0]);
        a2 += ex * __low2float(u.h2[1]);
        a3 += ex * __high2float(u.h2[1]);
        den += ex;
    }
    float inv = 1.f / (den + 1e-16f);

    float r0 = fmaxf((a0 * inv + bg[c0])     * (g[c0]     * BN_SCALE) + be[c0],     0.f);
    float r1 = fmaxf((a1 * inv + bg[c0 + 1]) * (g[c0 + 1] * BN_SCALE) + be[c0 + 1], 0.f);
    float r2 = fmaxf((a2 * inv + bg[c0 + 2]) * (g[c0 + 2] * BN_SCALE) + be[c0 + 2], 0.f);
    float r3 = fmaxf((a3 * inv + bg[c0 + 3]) * (g[c0 + 3] * BN_SCALE) + be[c0 + 3], 0.f);

    __half2* hp = (__half2*)(h + (size_t)n * HC + c0);
    if (residual) {
        __half2 o0 = hp[0], o1 = hp[1];
        r0 += __low2float(o0); r1 += __high2float(o0);
        r2 += __low2float(o1); r3 += __high2float(o1);
    }
    hp[0] = __floats2half2_rn(r0, r1);
    hp[1] = __floats2half2_rn(r2, r3);
}

// ---------------------------------------------------------------------------
// Final fused edge MLP (replaces edge_mlp):
// Phase 1: per block, 64 edges; MFMA computes z_pre = ea@W1e + b1 into LDS
//   (W1e pre-transposed to fp16 [n][k], ea cast fp32->fp16 in-register).
// Phase 2: 4 threads/edge gather hs[src], hd[dst] (half8 each), ReLU,
//   partial dot with W2, 2-step shfl reduce, add b2, store.
// Removes the old 32-iter serial LDS fmac chain (DS-pipe bound, 111 us).
// ---------------------------------------------------------------------------
__global__ __launch_bounds__(256) void edge_final(const float* __restrict__ ea,
                                                  const __half* __restrict__ w1et,
                                                  const float* __restrict__ b1,
                                                  const int* __restrict__ src,
                                                  const int* __restrict__ dst,
                                                  const __half* __restrict__ hshd,
                                                  const float* __restrict__ W2,
                                                  const float* __restrict__ b2,
                                                  float* __restrict__ out) {
    __shared__ float zl[64][36];   // stride 36: 16B-aligned rows, <=2-way banks
    const int wave = threadIdx.x >> 6, lane = threadIdx.x & 63;
    const int e0 = blockIdx.x * 64;
    const int lrow = lane & 15, kofs = (lane >> 4) * 8;

    // ---- Phase 1: MFMA z = ea @ W1e (K=32), 16 edges per wave ----
    int er = e0 + wave * 16 + lrow;
    if (er >= EE) er = EE - 1;
    const float* ap = ea + (size_t)er * F_EDGE + kofs;
    float4 f0 = *(const float4*)ap;
    float4 f1 = *(const float4*)(ap + 4);
    half8 a;
    a[0] = (_Float16)f0.x; a[1] = (_Float16)f0.y;
    a[2] = (_Float16)f0.z; a[3] = (_Float16)f0.w;
    a[4] = (_Float16)f1.x; a[5] = (_Float16)f1.y;
    a[6] = (_Float16)f1.z; a[7] = (_Float16)f1.w;

    half8 b0 = *(const half8*)(w1et + (size_t)lrow * 32 + kofs);
    half8 b1v = *(const half8*)(w1et + (size_t)(16 + lrow) * 32 + kofs);
    f32x4 acc0 = {}, acc1 = {};
    acc0 = __builtin_amdgcn_mfma_f32_16x16x32_f16(a, b0,  acc0, 0, 0, 0);
    acc1 = __builtin_amdgcn_mfma_f32_16x16x32_f16(a, b1v, acc1, 0, 0, 0);

    const int crow = (lane >> 4) * 4;
    const float bc0 = b1[lrow], bc1 = b1[16 + lrow];
#pragma unroll
    for (int r = 0; r < 4; ++r) {
        zl[wave * 16 + crow + r][lrow]      = acc0[r] + bc0;
        zl[wave * 16 + crow + r][16 + lrow] = acc1[r] + bc1;
    }
    __syncthreads();

    // ---- Phase 2: gather + ReLU + dot(W2) ----
    const int el = threadIdx.x >> 2, j0 = (threadIdx.x & 3) * 8;
    const int e = e0 + el;
    const bool ok = e < EE;
    const int s = ok ? src[e] : 0;
    const int d = ok ? dst[e] : 0;

    half8 hs = *(const half8*)(hshd + (size_t)s * 64 + j0);
    half8 hdv = *(const half8*)(hshd + (size_t)d * 64 + 32 + j0);
    float w2v[8];
    *(float4*)(w2v)     = *(const float4*)(W2 + j0);
    *(float4*)(w2v + 4) = *(const float4*)(W2 + j0 + 4);
    float4 z0 = *(const float4*)&zl[el][j0];
    float4 z1 = *(const float4*)&zl[el][j0 + 4];

    float acc = 0.f;
    const float* zp0 = &z0.x;
    const float* zp1 = &z1.x;
#pragma unroll
    for (int i = 0; i < 4; ++i) {
        float z = zp0[i] + (float)hs[i] + (float)hdv[i];
        acc += fmaxf(z, 0.f) * w2v[i];
    }
#pragma unroll
    for (int i = 0; i < 4; ++i) {
        float z = zp1[i] + (float)hs[4 + i] + (float)hdv[4 + i];
        acc += fmaxf(z, 0.f) * w2v[4 + i];
    }
    acc += __shfl_xor(acc, 1, 64);
    acc += __shfl_xor(acc, 2, 64);
    if (ok && (threadIdx.x & 3) == 0) out[e] = acc + b2[0];
}

// ---------------------------------------------------------------------------
extern "C" void kernel_launch(void* const* d_in, const int* in_sizes, int n_in,
                              void* d_out, int out_size, void* d_ws, size_t ws_size,
                              hipStream_t stream) {
    const float* x  = (const float*)d_in[0];
    const int*   ei = (const int*)d_in[1];
    const float* ea = (const float*)d_in[2];
    const float* Wp = (const float*)d_in[3];
    const float* bp = (const float*)d_in[4];
    const float* W1 = (const float*)d_in[23];
    const float* b1 = (const float*)d_in[24];
    const float* W2 = (const float*)d_in[25];
    const float* b2 = (const float*)d_in[26];
    const int* src = ei;
    const int* dst = ei + EE;

    // Workspace layout (float-granular offsets; total ~43.2M f = 172.8 MB)
    float* ws = (float*)d_ws;
    __half* h      = (__half*)(ws);              // 25.6M halfs
    __half* xh     = (__half*)(ws + 12800000);
    __half* x16    = (__half*)(ws + 25600000);   // 12.8M halfs
    __half* h0     = (__half*)(ws + 32000000);   // 6.4M halfs
    __half* hshd   = (__half*)(ws + 35200000);   // 6.4M halfs
    float*  a_s    = ws + 38400000;
    float*  a_d    = ws + 38800000;
    float*  exs    = ws + 39200000;              // 2M f
    int*    rowptr = (int*)(ws + 41200000);
    int*    deg    = (int*)(ws + 41400000);
    int*    pos    = (int*)(ws + 41600000);
    int*    perm   = (int*)(ws + 42100000);
    int*    srcs   = (int*)(ws + 42600000);
    int*    bsum   = (int*)(ws + 43100000);
    int*    boff   = (int*)(ws + 43101000);
    __half* wpt    = (__half*)(ws + 43102000);   // 64x128 (reused as w1et at end)
    __half* wgt    = (__half*)(ws + 43110000);   // 256x256 (reused per layer)
    __half* w1t    = (__half*)(ws + 43150000);   // 64x256
    float*  out    = (float*)d_out;

    // ---- CSR build (once) ----
    hipMemsetAsync(deg, 0, (size_t)NN * sizeof(int), stream);
    csr_count<<<(EE + 255) / 256, 256, 0, stream>>>(dst, deg, pos);
    scan1<<<NB_SCAN, 256, 0, stream>>>(deg, rowptr, bsum);
    scan2<<<1, 512, 0, stream>>>(bsum, boff);
    scan3<<<NB_SCAN, 256, 0, stream>>>(rowptr, boff);
    csr_scatter<<<(EE + 255) / 256, 256, 0, stream>>>(src, dst, rowptr, pos, perm, srcs);

    // ---- prep: x->fp16, Wp^T ----
    cvt_x<<<NN * F_NODE / 4 / 256, 256, 0, stream>>>(x, x16);
    wt_conv<<<(F_NODE * 64 + 255) / 256, 256, 0, stream>>>(Wp, wpt, F_NODE, 64);

    // h0 = relu(x @ Wp + bp)
    mgemm<F_NODE, 64, 1><<<NN / 32, 256, 0, stream>>>(x16, wpt, bp, h0);

    for (int l = 0; l < 3; ++l) {
        const float* Wg  = (const float*)d_in[5 + 6 * l];
        const float* as_ = (const float*)d_in[6 + 6 * l];
        const float* ad_ = (const float*)d_in[7 + 6 * l];
        const float* bg  = (const float*)d_in[8 + 6 * l];
        const float* g   = (const float*)d_in[9 + 6 * l];
        const float* be  = (const float*)d_in[10 + 6 * l];

        if (l == 0) {
            wt_conv<<<(CC * HC + 255) / 256, 256, 0, stream>>>(Wg, wgt, CC, HC);
            mgemm<CC, HC, 0><<<NN / 32, 256, 0, stream>>>(h0, wgt, nullptr, xh);
        } else {
            wt_conv<<<(HC * HC + 255) / 256, 256, 0, stream>>>(Wg, wgt, HC, HC);
            mgemm<HC, HC, 0><<<NN / 32, 256, 0, stream>>>(h, wgt, nullptr, xh);
        }

        att_score<<<NN / 4, 256, 0, stream>>>(xh, as_, ad_, a_s, a_d);
        edge_score<<<(EE * HEADS + 255) / 256, 256, 0, stream>>>(src, dst, perm, a_s, a_d, exs);
        gather_agg<<<(NN + 3) / 4, 256, 0, stream>>>(rowptr, srcs, exs, xh, bg, g, be, h, l > 0 ? 1 : 0);
    }

    // hs|hd = h @ [W1s | W1d]
    wt_final<<<(64 * 256 + 255) / 256, 256, 0, stream>>>(W1, w1t);
    mgemm<HC, 64, 0><<<NN / 32, 256, 0, stream>>>(h, w1t, nullptr, hshd);

    // W1e^T -> fp16 (reuse wpt; mgemm that used it is long done, stream-ordered)
    wt_conv<<<(32 * 32 + 255) / 256, 256, 0, stream>>>(W1 + 2 * HC * OUTD, wpt, 32, 32);
    edge_final<<<(EE + 63) / 64, 256, 0, stream>>>(ea, wpt, b1, src, dst, hshd, W2, b2, out);
}

// Round 2
// 504.757 us; speedup vs baseline: 1.3995x; 1.2562x over previous
//
#include <hip/hip_runtime.h>
#include <hip/hip_fp16.h>

// Problem constants
#define NN 100000
#define EE 500000
#define F_NODE 128
#define F_EDGE 32
#define HEADS 4
#define CC 64
#define HC 256
#define OUTD 32
#define NEG_SLOPE 0.2f
#define BN_SCALE 0.9999950000374997f   // 1/sqrt(1+1e-5)
#define NB_SCAN 391                    // ceil(NN/256)
#define MPAD 100096                    // NN padded to multiple of 128

using half8 = __attribute__((ext_vector_type(8))) _Float16;
using f32x4 = __attribute__((ext_vector_type(4))) float;

typedef const __attribute__((address_space(1))) void* gas_ptr;
typedef __attribute__((address_space(3))) void* las_ptr;

// ---------------------------------------------------------------------------
// Tiled MFMA GEMM: C[m][n] = sum_k A[m][k] * Wt[n][k]
//   A fp16 [M][K] row-major (M padded to >= grid*128 rows, garbage pad ok)
//   Wt fp16 [NOUT][K] row-major (weights pre-transposed)
//   C fp16 [M][NOUT] (padded; pad rows receive garbage, never read)
// Tile: BM=128 x BN=(128 or 64), BK=64. 4 waves in 2x2; each wave owns
// 64 x (BN/2) output = MIxNI 16x16 fragments.
// LDS: double-buffered A[128][64] + B[BN][64] fp16, linear dest via
// global_load_lds(16B), XOR-swizzled SOURCE (unit ^= row&7) and the same
// XOR applied on ds_read_b128 -> 2-way banks (free) instead of 16-way.
// One barrier per K-step, stage-ahead prefetch (m97 2-phase structure).
// MODE 1: + bias[col], ReLU.
// ---------------------------------------------------------------------------
template<int K, int NOUT, int MODE>
__global__ __launch_bounds__(256, 2) void mgemm2(const __half* __restrict__ A,
                                                 const __half* __restrict__ Wt,
                                                 const float* __restrict__ bias,
                                                 __half* __restrict__ C) {
    constexpr int BM = 128;
    constexpr int BN = (NOUT >= 128) ? 128 : 64;
    constexpr int MI = 4;
    constexpr int NI = BN / 32;
    constexpr int KS = K / 64;
    constexpr int ABYTES = BM * 128;   // 128 rows x 64 halfs
    constexpr int BBYTES = BN * 128;
    __shared__ char smem[2 * (ABYTES + BBYTES)];

    const int tid  = threadIdx.x;
    const int wave = tid >> 6, lane = tid & 63;
    const int wr = wave >> 1, wc = wave & 1;
    const int lrow = lane & 15, kq = lane >> 4;
    const int m0 = blockIdx.x * BM;
    const int n0 = blockIdx.y * BN;
    const int srow = tid >> 3;         // 0..31 staging row within 32-row slab
    const int sunit = tid & 7;         // physical 16B unit within row
    const int wofs = (tid & 192) * 16; // wave-uniform LDS offset (w*1024)

    // stage one BK=64 tile of A and B into buffer `buf`
    auto stage = [&](int buf, int ks) {
        char* base = smem + buf * (ABYTES + BBYTES);
        const int kk = ks * 64;
#pragma unroll
        for (int it = 0; it < BM / 32; ++it) {
            const int r = srow + it * 32;
            const __half* src = A + (size_t)(m0 + r) * K + kk + ((sunit ^ (r & 7)) << 3);
            __builtin_amdgcn_global_load_lds((gas_ptr)src,
                (las_ptr)(base + it * 4096 + wofs), 16, 0, 0);
        }
#pragma unroll
        for (int it = 0; it < BN / 32; ++it) {
            const int r = srow + it * 32;
            const __half* src = Wt + (size_t)(n0 + r) * K + kk + ((sunit ^ (r & 7)) << 3);
            __builtin_amdgcn_global_load_lds((gas_ptr)src,
                (las_ptr)(base + ABYTES + it * 4096 + wofs), 16, 0, 0);
        }
    };

    f32x4 acc[MI][NI] = {};

    auto compute = [&](int buf) {
        const char* Ab = smem + buf * (ABYTES + BBYTES);
        const char* Bb = Ab + ABYTES;
#pragma unroll
        for (int k32 = 0; k32 < 2; ++k32) {
            const int ku = k32 * 4 + kq;       // logical 16B unit (0..7)
            half8 af[MI], bf[NI];
#pragma unroll
            for (int mi = 0; mi < MI; ++mi) {
                const int rr = wr * 64 + mi * 16 + lrow;
                af[mi] = *(const half8*)(Ab + rr * 128 + ((ku ^ (rr & 7)) << 4));
            }
#pragma unroll
            for (int ni = 0; ni < NI; ++ni) {
                const int rc = wc * (BN / 2) + ni * 16 + lrow;
                bf[ni] = *(const half8*)(Bb + rc * 128 + ((ku ^ (rc & 7)) << 4));
            }
#pragma unroll
            for (int mi = 0; mi < MI; ++mi)
#pragma unroll
                for (int ni = 0; ni < NI; ++ni)
                    acc[mi][ni] = __builtin_amdgcn_mfma_f32_16x16x32_f16(
                        af[mi], bf[ni], acc[mi][ni], 0, 0, 0);
        }
    };

    stage(0, 0);
    __syncthreads();                    // drain prologue stage
    int cur = 0;
#pragma unroll
    for (int ks = 0; ks < KS; ++ks) {
        if (ks + 1 < KS) stage(cur ^ 1, ks + 1);
        compute(cur);
        __syncthreads();                // drains next stage + guards re-stage
        cur ^= 1;
    }

    const int crow = kq * 4;
#pragma unroll
    for (int mi = 0; mi < MI; ++mi) {
#pragma unroll
        for (int ni = 0; ni < NI; ++ni) {
            const int col = n0 + wc * (BN / 2) + ni * 16 + lrow;
            float bcol = (MODE == 1) ? bias[col] : 0.f;
#pragma unroll
            for (int r = 0; r < 4; ++r) {
                float v = acc[mi][ni][r];
                if constexpr (MODE == 1) v = fmaxf(v + bcol, 0.f);
                const int row = m0 + wr * 64 + mi * 16 + crow + r;
                C[(size_t)row * NOUT + col] = __float2half(v);
            }
        }
    }
}

// ---------------------------------------------------------------------------
// Prep kernels: transpose-convert weights to fp16 NxK, cast x to fp16.
// ---------------------------------------------------------------------------
__global__ __launch_bounds__(256) void wt_conv(const float* __restrict__ W,
                                               __half* __restrict__ Wt,
                                               int K, int N) {
    int idx = blockIdx.x * 256 + threadIdx.x;   // over N*K, output-contiguous
    if (idx >= K * N) return;
    int n = idx / K, k = idx % K;
    Wt[idx] = __float2half(W[k * N + n]);
}

// Wt_final[n][k]: n<32 -> W1[k][n] (W1s), n>=32 -> W1[256+k][n-32] (W1d)
__global__ __launch_bounds__(256) void wt_final(const float* __restrict__ W1,
                                                __half* __restrict__ Wt) {
    int idx = blockIdx.x * 256 + threadIdx.x;   // over 64*256
    if (idx >= 64 * 256) return;
    int n = idx >> 8, k = idx & 255;
    float v = (n < 32) ? W1[k * 32 + n] : W1[(256 + k) * 32 + (n - 32)];
    Wt[idx] = __float2half(v);
}

__global__ __launch_bounds__(256) void cvt_x(const float* __restrict__ x,
                                             __half* __restrict__ x16) {
    int i = blockIdx.x * 256 + threadIdx.x;     // over NN*F_NODE/4
    float4 v = ((const float4*)x)[i];
    __half2* o = (__half2*)x16 + (size_t)i * 2;
    o[0] = __floats2half2_rn(v.x, v.y);
    o[1] = __floats2half2_rn(v.z, v.w);
}

// ---------------------------------------------------------------------------
// CSR build: deg-count, two-level exclusive scan, scatter.
// ---------------------------------------------------------------------------
__global__ __launch_bounds__(256) void csr_count(const int* __restrict__ dst,
                                                 int* __restrict__ deg,
                                                 int* __restrict__ pos) {
    int e = blockIdx.x * 256 + threadIdx.x;
    if (e >= EE) return;
    pos[e] = atomicAdd(deg + dst[e], 1);
}

__device__ __forceinline__ int wave_incl_scan(int v, int lane) {
#pragma unroll
    for (int off = 1; off < 64; off <<= 1) {
        int t = __shfl_up(v, off, 64);
        if (lane >= off) v += t;
    }
    return v;
}

__global__ __launch_bounds__(256) void scan1(const int* __restrict__ deg,
                                             int* __restrict__ rowptr,
                                             int* __restrict__ bsum) {
    int tid = threadIdx.x, n = blockIdx.x * 256 + tid;
    int lane = tid & 63, wave = tid >> 6;
    int d = (n < NN) ? deg[n] : 0;
    int v = wave_incl_scan(d, lane);
    __shared__ int ws[4];
    if (lane == 63) ws[wave] = v;
    __syncthreads();
    int woff = 0;
    for (int w = 0; w < wave; ++w) woff += ws[w];
    int incl = v + woff;
    if (n < NN) rowptr[n] = incl - d;
    if (tid == 255) bsum[blockIdx.x] = incl;
}

__global__ __launch_bounds__(512) void scan2(const int* __restrict__ bsum,
                                             int* __restrict__ boff) {
    int t = threadIdx.x;
    int lane = t & 63, wave = t >> 6;
    int d = (t < NB_SCAN) ? bsum[t] : 0;
    int v = wave_incl_scan(d, lane);
    __shared__ int ws[8];
    if (lane == 63) ws[wave] = v;
    __syncthreads();
    int woff = 0;
    for (int w = 0; w < wave; ++w) woff += ws[w];
    if (t < NB_SCAN) boff[t] = v + woff - d;
}

__global__ __launch_bounds__(256) void scan3(int* __restrict__ rowptr,
                                             const int* __restrict__ boff) {
    int n = blockIdx.x * 256 + threadIdx.x;
    if (n == 0) rowptr[NN] = EE;
    if (n < NN) rowptr[n] += boff[blockIdx.x];
}

__global__ __launch_bounds__(256) void csr_scatter(const int* __restrict__ src,
                                                   const int* __restrict__ dst,
                                                   const int* __restrict__ rowptr,
                                                   const int* __restrict__ pos,
                                                   int* __restrict__ perm,
                                                   int* __restrict__ srcs) {
    int e = blockIdx.x * 256 + threadIdx.x;
    if (e >= EE) return;
    int p = rowptr[dst[e]] + pos[e];
    perm[e] = p;
    srcs[p] = src[e];
}

// ---------------------------------------------------------------------------
// a_s[n][h] = sum_c xh[n][h*64+c]*att_s[h*64+c]; same for a_d.
// ---------------------------------------------------------------------------
__global__ __launch_bounds__(256) void att_score(const __half* __restrict__ xh,
                                                 const float* __restrict__ as_,
                                                 const float* __restrict__ ad_,
                                                 float* __restrict__ a_s,
                                                 float* __restrict__ a_d) {
    const int lane = threadIdx.x & 63, wave = threadIdx.x >> 6;
    const int n = blockIdx.x * 4 + wave;
    const int c0 = lane * 4;

    float ws0 = as_[c0], ws1 = as_[c0 + 1], ws2 = as_[c0 + 2], ws3 = as_[c0 + 3];
    float wd0 = ad_[c0], wd1 = ad_[c0 + 1], wd2 = ad_[c0 + 2], wd3 = ad_[c0 + 3];

    const __half2* p = (const __half2*)(xh + (size_t)n * HC);
    __half2 v0 = p[lane * 2], v1 = p[lane * 2 + 1];
    float x0 = __low2float(v0), x1 = __high2float(v0);
    float x2 = __low2float(v1), x3 = __high2float(v1);

    float ss = x0 * ws0 + x1 * ws1 + x2 * ws2 + x3 * ws3;
    float dd = x0 * wd0 + x1 * wd1 + x2 * wd2 + x3 * wd3;
#pragma unroll
    for (int m = 8; m >= 1; m >>= 1) {
        ss += __shfl_xor(ss, m, 64);
        dd += __shfl_xor(dd, m, 64);
    }
    if ((lane & 15) == 0) {
        a_s[n * HEADS + (lane >> 4)] = ss;
        a_d[n * HEADS + (lane >> 4)] = dd;
    }
}

// ---------------------------------------------------------------------------
// Per (edge, head): ex = exp(leaky_relu(a_s[src]+a_d[dst])), written to the
// CSR-sorted slot (softmax shift-invariant; logits tiny -> no segment_max).
// ---------------------------------------------------------------------------
__global__ __launch_bounds__(256) void edge_score(const int* __restrict__ src,
                                                  const int* __restrict__ dst,
                                                  const int* __restrict__ perm,
                                                  const float* __restrict__ a_s,
                                                  const float* __restrict__ a_d,
                                                  float* __restrict__ exs) {
    int idx = blockIdx.x * 256 + threadIdx.x;
    if (idx >= EE * HEADS) return;
    int e = idx >> 2, h = idx & 3;
    int s = src[e], d = dst[e];
    float v = a_s[s * HEADS + h] + a_d[d * HEADS + h];
    v = (v > 0.f) ? v : v * NEG_SLOPE;
    exs[perm[e] * HEADS + h] = __expf(v);
}

// ---------------------------------------------------------------------------
// Gather-aggregate + fused BN/ReLU/residual. One wave per dst node, no atomics.
// ---------------------------------------------------------------------------
__global__ __launch_bounds__(256) void gather_agg(const int* __restrict__ rowptr,
                                                  const int* __restrict__ srcs,
                                                  const float* __restrict__ exs,
                                                  const __half* __restrict__ xh,
                                                  const float* __restrict__ bg,
                                                  const float* __restrict__ g,
                                                  const float* __restrict__ be,
                                                  __half* __restrict__ h,
                                                  int residual) {
    const int n = blockIdx.x * 4 + (threadIdx.x >> 6);
    const int lane = threadIdx.x & 63;
    if (n >= NN) return;
    const int hd = lane >> 4;
    const int c0 = lane * 4;

    const int start = rowptr[n], end = rowptr[n + 1];
    float a0 = 0.f, a1 = 0.f, a2 = 0.f, a3 = 0.f, den = 0.f;
    for (int i = start; i < end; ++i) {
        float ex = exs[i * HEADS + hd];
        int s = srcs[i];
        union { float2 f2; __half2 h2[2]; } u;
        u.f2 = *(const float2*)(xh + (size_t)s * HC + c0);
        a0 += ex * __low2float(u.h2[0]);
        a1 += ex * __high2float(u.h2[0]);
        a2 += ex * __low2float(u.h2[1]);
        a3 += ex * __high2float(u.h2[1]);
        den += ex;
    }
    float inv = 1.f / (den + 1e-16f);

    float r0 = fmaxf((a0 * inv + bg[c0])     * (g[c0]     * BN_SCALE) + be[c0],     0.f);
    float r1 = fmaxf((a1 * inv + bg[c0 + 1]) * (g[c0 + 1] * BN_SCALE) + be[c0 + 1], 0.f);
    float r2 = fmaxf((a2 * inv + bg[c0 + 2]) * (g[c0 + 2] * BN_SCALE) + be[c0 + 2], 0.f);
    float r3 = fmaxf((a3 * inv + bg[c0 + 3]) * (g[c0 + 3] * BN_SCALE) + be[c0 + 3], 0.f);

    __half2* hp = (__half2*)(h + (size_t)n * HC + c0);
    if (residual) {
        __half2 o0 = hp[0], o1 = hp[1];
        r0 += __low2float(o0); r1 += __high2float(o0);
        r2 += __low2float(o1); r3 += __high2float(o1);
    }
    hp[0] = __floats2half2_rn(r0, r1);
    hp[1] = __floats2half2_rn(r2, r3);
}

// ---------------------------------------------------------------------------
// Final fused edge MLP:
// Phase 1: per block, 64 edges; MFMA computes z_pre = ea@W1e + b1 into LDS.
// Phase 2: 4 threads/edge gather hs[src], hd[dst], ReLU, dot(W2), reduce.
// ---------------------------------------------------------------------------
__global__ __launch_bounds__(256) void edge_final(const float* __restrict__ ea,
                                                  const __half* __restrict__ w1et,
                                                  const float* __restrict__ b1,
                                                  const int* __restrict__ src,
                                                  const int* __restrict__ dst,
                                                  const __half* __restrict__ hshd,
                                                  const float* __restrict__ W2,
                                                  const float* __restrict__ b2,
                                                  float* __restrict__ out) {
    __shared__ float zl[64][36];   // stride 36: 16B-aligned rows, <=2-way banks
    const int wave = threadIdx.x >> 6, lane = threadIdx.x & 63;
    const int e0 = blockIdx.x * 64;
    const int lrow = lane & 15, kofs = (lane >> 4) * 8;

    // ---- Phase 1: MFMA z = ea @ W1e (K=32), 16 edges per wave ----
    int er = e0 + wave * 16 + lrow;
    if (er >= EE) er = EE - 1;
    const float* ap = ea + (size_t)er * F_EDGE + kofs;
    float4 f0 = *(const float4*)ap;
    float4 f1 = *(const float4*)(ap + 4);
    half8 a;
    a[0] = (_Float16)f0.x; a[1] = (_Float16)f0.y;
    a[2] = (_Float16)f0.z; a[3] = (_Float16)f0.w;
    a[4] = (_Float16)f1.x; a[5] = (_Float16)f1.y;
    a[6] = (_Float16)f1.z; a[7] = (_Float16)f1.w;

    half8 b0 = *(const half8*)(w1et + (size_t)lrow * 32 + kofs);
    half8 b1v = *(const half8*)(w1et + (size_t)(16 + lrow) * 32 + kofs);
    f32x4 acc0 = {}, acc1 = {};
    acc0 = __builtin_amdgcn_mfma_f32_16x16x32_f16(a, b0,  acc0, 0, 0, 0);
    acc1 = __builtin_amdgcn_mfma_f32_16x16x32_f16(a, b1v, acc1, 0, 0, 0);

    const int crow = (lane >> 4) * 4;
    const float bc0 = b1[lrow], bc1 = b1[16 + lrow];
#pragma unroll
    for (int r = 0; r < 4; ++r) {
        zl[wave * 16 + crow + r][lrow]      = acc0[r] + bc0;
        zl[wave * 16 + crow + r][16 + lrow] = acc1[r] + bc1;
    }
    __syncthreads();

    // ---- Phase 2: gather + ReLU + dot(W2) ----
    const int el = threadIdx.x >> 2, j0 = (threadIdx.x & 3) * 8;
    const int e = e0 + el;
    const bool ok = e < EE;
    const int s = ok ? src[e] : 0;
    const int d = ok ? dst[e] : 0;

    half8 hs = *(const half8*)(hshd + (size_t)s * 64 + j0);
    half8 hdv = *(const half8*)(hshd + (size_t)d * 64 + 32 + j0);
    float w2v[8];
    *(float4*)(w2v)     = *(const float4*)(W2 + j0);
    *(float4*)(w2v + 4) = *(const float4*)(W2 + j0 + 4);
    float4 z0 = *(const float4*)&zl[el][j0];
    float4 z1 = *(const float4*)&zl[el][j0 + 4];

    float acc = 0.f;
    const float* zp0 = &z0.x;
    const float* zp1 = &z1.x;
#pragma unroll
    for (int i = 0; i < 4; ++i) {
        float z = zp0[i] + (float)hs[i] + (float)hdv[i];
        acc += fmaxf(z, 0.f) * w2v[i];
    }
#pragma unroll
    for (int i = 0; i < 4; ++i) {
        float z = zp1[i] + (float)hs[4 + i] + (float)hdv[4 + i];
        acc += fmaxf(z, 0.f) * w2v[4 + i];
    }
    acc += __shfl_xor(acc, 1, 64);
    acc += __shfl_xor(acc, 2, 64);
    if (ok && (threadIdx.x & 3) == 0) out[e] = acc + b2[0];
}

// ---------------------------------------------------------------------------
extern "C" void kernel_launch(void* const* d_in, const int* in_sizes, int n_in,
                              void* d_out, int out_size, void* d_ws, size_t ws_size,
                              hipStream_t stream) {
    const float* x  = (const float*)d_in[0];
    const int*   ei = (const int*)d_in[1];
    const float* ea = (const float*)d_in[2];
    const float* Wp = (const float*)d_in[3];
    const float* bp = (const float*)d_in[4];
    const float* W1 = (const float*)d_in[23];
    const float* b1 = (const float*)d_in[24];
    const float* W2 = (const float*)d_in[25];
    const float* b2 = (const float*)d_in[26];
    const int* src = ei;
    const int* dst = ei + EE;

    // Workspace layout (float offsets). All matrix buffers padded to MPAD
    // rows so the 782-block (128-row) GEMM grid needs no bounds checks.
    float* ws = (float*)d_ws;
    __half* h      = (__half*)(ws);               // MPAD*256 halfs
    __half* xh     = (__half*)(ws + 12820000);    // MPAD*256 halfs
    __half* x16    = (__half*)(ws + 25640000);    // MPAD*128 halfs
    __half* h0     = (__half*)(ws + 32050000);    // MPAD*64 halfs
    __half* hshd   = (__half*)(ws + 35260000);    // MPAD*64 halfs
    float*  a_s    = ws + 38470000;               // NN*4
    float*  a_d    = ws + 38870000;               // NN*4
    float*  exs    = ws + 39270000;               // EE*4
    int*    rowptr = (int*)(ws + 41270000);       // NN+1
    int*    deg    = (int*)(ws + 41380000);       // NN
    int*    pos    = (int*)(ws + 41480000);       // EE
    int*    perm   = (int*)(ws + 41990000);       // EE
    int*    srcs   = (int*)(ws + 42490000);       // EE
    int*    bsum   = (int*)(ws + 42990000);       // NB_SCAN
    int*    boff   = (int*)(ws + 42991000);       // NB_SCAN
    __half* wpt    = (__half*)(ws + 42992000);    // 64x128 (reused as w1et)
    __half* wgt    = (__half*)(ws + 43000000);    // 256x256
    __half* w1t    = (__half*)(ws + 43020000);    // 64x256
    float*  out    = (float*)d_out;

    const int MB = MPAD / 128;   // 782 row-blocks

    // ---- CSR build (once) ----
    hipMemsetAsync(deg, 0, (size_t)NN * sizeof(int), stream);
    csr_count<<<(EE + 255) / 256, 256, 0, stream>>>(dst, deg, pos);
    scan1<<<NB_SCAN, 256, 0, stream>>>(deg, rowptr, bsum);
    scan2<<<1, 512, 0, stream>>>(bsum, boff);
    scan3<<<NB_SCAN, 256, 0, stream>>>(rowptr, boff);
    csr_scatter<<<(EE + 255) / 256, 256, 0, stream>>>(src, dst, rowptr, pos, perm, srcs);

    // ---- prep: x->fp16, Wp^T ----
    cvt_x<<<NN * F_NODE / 4 / 256, 256, 0, stream>>>(x, x16);
    wt_conv<<<(F_NODE * 64 + 255) / 256, 256, 0, stream>>>(Wp, wpt, F_NODE, 64);

    // h0 = relu(x @ Wp + bp)
    mgemm2<F_NODE, 64, 1><<<dim3(MB, 1), 256, 0, stream>>>(x16, wpt, bp, h0);

    for (int l = 0; l < 3; ++l) {
        const float* Wg  = (const float*)d_in[5 + 6 * l];
        const float* as_ = (const float*)d_in[6 + 6 * l];
        const float* ad_ = (const float*)d_in[7 + 6 * l];
        const float* bg  = (const float*)d_in[8 + 6 * l];
        const float* g   = (const float*)d_in[9 + 6 * l];
        const float* be  = (const float*)d_in[10 + 6 * l];

        if (l == 0) {
            wt_conv<<<(CC * HC + 255) / 256, 256, 0, stream>>>(Wg, wgt, CC, HC);
            mgemm2<CC, HC, 0><<<dim3(MB, 2), 256, 0, stream>>>(h0, wgt, nullptr, xh);
        } else {
            wt_conv<<<(HC * HC + 255) / 256, 256, 0, stream>>>(Wg, wgt, HC, HC);
            mgemm2<HC, HC, 0><<<dim3(MB, 2), 256, 0, stream>>>(h, wgt, nullptr, xh);
        }

        att_score<<<NN / 4, 256, 0, stream>>>(xh, as_, ad_, a_s, a_d);
        edge_score<<<(EE * HEADS + 255) / 256, 256, 0, stream>>>(src, dst, perm, a_s, a_d, exs);
        gather_agg<<<(NN + 3) / 4, 256, 0, stream>>>(rowptr, srcs, exs, xh, bg, g, be, h, l > 0 ? 1 : 0);
    }

    // hs|hd = h @ [W1s | W1d]
    wt_final<<<(64 * 256 + 255) / 256, 256, 0, stream>>>(W1, w1t);
    mgemm2<HC, 64, 0><<<dim3(MB, 1), 256, 0, stream>>>(h, w1t, nullptr, hshd);

    // W1e^T -> fp16 (reuse wpt; first mgemm2 that used it is long done)
    wt_conv<<<(32 * 32 + 255) / 256, 256, 0, stream>>>(W1 + 2 * HC * OUTD, wpt, 32, 32);
    edge_final<<<(EE + 63) / 64, 256, 0, stream>>>(ea, wpt, b1, src, dst, hshd, W2, b2, out);
}

// Round 3
// 447.903 us; speedup vs baseline: 1.5772x; 1.1269x over previous
//
#include <hip/hip_runtime.h>
#include <hip/hip_fp16.h>

// Problem constants
#define NN 100000
#define EE 500000
#define F_NODE 128
#define F_EDGE 32
#define HEADS 4
#define CC 64
#define HC 256
#define OUTD 32
#define NEG_SLOPE 0.2f
#define BN_SCALE 0.9999950000374997f   // 1/sqrt(1+1e-5)
#define NB_SCAN 391                    // ceil(NN/256)
#define MPAD 100096                    // NN padded to multiple of 128

using half8 = __attribute__((ext_vector_type(8))) _Float16;
using f32x4 = __attribute__((ext_vector_type(4))) float;

typedef const __attribute__((address_space(1))) void* gas_ptr;
typedef __attribute__((address_space(3))) void* las_ptr;

// ---------------------------------------------------------------------------
// Tiled MFMA GEMM: C[m][n] = sum_k A[m][k] * Wt[n][k]
//   A fp16 [M][K] row-major (M padded to >= grid*128 rows, garbage pad ok)
//   Wt fp16 [NOUT][K] row-major (weights pre-transposed)
//   C fp16 [M][NOUT] (padded; pad rows receive garbage, never read)
// Tile: BM=128 x BN=(128 or 64), BK=64. 4 waves in 2x2; each wave owns
// 64 x (BN/2) output = MIxNI 16x16 fragments.
// LDS: double-buffered A[128][64] + B[BN][64] fp16, linear dest via
// global_load_lds(16B), XOR-swizzled SOURCE (unit ^= row&7) and the same
// XOR applied on ds_read_b128 -> 2-way banks (free) instead of 16-way.
// One barrier per K-step, stage-ahead prefetch (m97 2-phase structure).
// MODE 1: + bias[col], ReLU.
// ---------------------------------------------------------------------------
template<int K, int NOUT, int MODE>
__global__ __launch_bounds__(256, 2) void mgemm2(const __half* __restrict__ A,
                                                 const __half* __restrict__ Wt,
                                                 const float* __restrict__ bias,
                                                 __half* __restrict__ C) {
    constexpr int BM = 128;
    constexpr int BN = (NOUT >= 128) ? 128 : 64;
    constexpr int MI = 4;
    constexpr int NI = BN / 32;
    constexpr int KS = K / 64;
    constexpr int ABYTES = BM * 128;   // 128 rows x 64 halfs
    constexpr int BBYTES = BN * 128;
    __shared__ char smem[2 * (ABYTES + BBYTES)];

    const int tid  = threadIdx.x;
    const int wave = tid >> 6, lane = tid & 63;
    const int wr = wave >> 1, wc = wave & 1;
    const int lrow = lane & 15, kq = lane >> 4;
    const int m0 = blockIdx.x * BM;
    const int n0 = blockIdx.y * BN;
    const int srow = tid >> 3;         // 0..31 staging row within 32-row slab
    const int sunit = tid & 7;         // physical 16B unit within row
    const int wofs = (tid & 192) * 16; // wave-uniform LDS offset (w*1024)

    // stage one BK=64 tile of A and B into buffer `buf`
    auto stage = [&](int buf, int ks) {
        char* base = smem + buf * (ABYTES + BBYTES);
        const int kk = ks * 64;
#pragma unroll
        for (int it = 0; it < BM / 32; ++it) {
            const int r = srow + it * 32;
            const __half* src = A + (size_t)(m0 + r) * K + kk + ((sunit ^ (r & 7)) << 3);
            __builtin_amdgcn_global_load_lds((gas_ptr)src,
                (las_ptr)(base + it * 4096 + wofs), 16, 0, 0);
        }
#pragma unroll
        for (int it = 0; it < BN / 32; ++it) {
            const int r = srow + it * 32;
            const __half* src = Wt + (size_t)(n0 + r) * K + kk + ((sunit ^ (r & 7)) << 3);
            __builtin_amdgcn_global_load_lds((gas_ptr)src,
                (las_ptr)(base + ABYTES + it * 4096 + wofs), 16, 0, 0);
        }
    };

    f32x4 acc[MI][NI] = {};

    auto compute = [&](int buf) {
        const char* Ab = smem + buf * (ABYTES + BBYTES);
        const char* Bb = Ab + ABYTES;
#pragma unroll
        for (int k32 = 0; k32 < 2; ++k32) {
            const int ku = k32 * 4 + kq;       // logical 16B unit (0..7)
            half8 af[MI], bf[NI];
#pragma unroll
            for (int mi = 0; mi < MI; ++mi) {
                const int rr = wr * 64 + mi * 16 + lrow;
                af[mi] = *(const half8*)(Ab + rr * 128 + ((ku ^ (rr & 7)) << 4));
            }
#pragma unroll
            for (int ni = 0; ni < NI; ++ni) {
                const int rc = wc * (BN / 2) + ni * 16 + lrow;
                bf[ni] = *(const half8*)(Bb + rc * 128 + ((ku ^ (rc & 7)) << 4));
            }
#pragma unroll
            for (int mi = 0; mi < MI; ++mi)
#pragma unroll
                for (int ni = 0; ni < NI; ++ni)
                    acc[mi][ni] = __builtin_amdgcn_mfma_f32_16x16x32_f16(
                        af[mi], bf[ni], acc[mi][ni], 0, 0, 0);
        }
    };

    stage(0, 0);
    __syncthreads();                    // drain prologue stage
    int cur = 0;
#pragma unroll
    for (int ks = 0; ks < KS; ++ks) {
        if (ks + 1 < KS) stage(cur ^ 1, ks + 1);
        compute(cur);
        __syncthreads();                // drains next stage + guards re-stage
        cur ^= 1;
    }

    const int crow = kq * 4;
#pragma unroll
    for (int mi = 0; mi < MI; ++mi) {
#pragma unroll
        for (int ni = 0; ni < NI; ++ni) {
            const int col = n0 + wc * (BN / 2) + ni * 16 + lrow;
            float bcol = (MODE == 1) ? bias[col] : 0.f;
#pragma unroll
            for (int r = 0; r < 4; ++r) {
                float v = acc[mi][ni][r];
                if constexpr (MODE == 1) v = fmaxf(v + bcol, 0.f);
                const int row = m0 + wr * 64 + mi * 16 + crow + r;
                C[(size_t)row * NOUT + col] = __float2half(v);
            }
        }
    }
}

// ---------------------------------------------------------------------------
// Prep kernels: transpose-convert weights to fp16 NxK, cast x to fp16.
// ---------------------------------------------------------------------------
__global__ __launch_bounds__(256) void wt_conv(const float* __restrict__ W,
                                               __half* __restrict__ Wt,
                                               int K, int N) {
    int idx = blockIdx.x * 256 + threadIdx.x;   // over N*K, output-contiguous
    if (idx >= K * N) return;
    int n = idx / K, k = idx % K;
    Wt[idx] = __float2half(W[k * N + n]);
}

// Wt_final[n][k]: n<32 -> W1[k][n] (W1s), n>=32 -> W1[256+k][n-32] (W1d)
__global__ __launch_bounds__(256) void wt_final(const float* __restrict__ W1,
                                                __half* __restrict__ Wt) {
    int idx = blockIdx.x * 256 + threadIdx.x;   // over 64*256
    if (idx >= 64 * 256) return;
    int n = idx >> 8, k = idx & 255;
    float v = (n < 32) ? W1[k * 32 + n] : W1[(256 + k) * 32 + (n - 32)];
    Wt[idx] = __float2half(v);
}

__global__ __launch_bounds__(256) void cvt_x(const float* __restrict__ x,
                                             __half* __restrict__ x16) {
    int i = blockIdx.x * 256 + threadIdx.x;     // over NN*F_NODE/4
    float4 v = ((const float4*)x)[i];
    __half2* o = (__half2*)x16 + (size_t)i * 2;
    o[0] = __floats2half2_rn(v.x, v.y);
    o[1] = __floats2half2_rn(v.z, v.w);
}

// ---------------------------------------------------------------------------
// CSR build: deg-count, two-level exclusive scan, scatter.
// ---------------------------------------------------------------------------
__global__ __launch_bounds__(256) void csr_count(const int* __restrict__ dst,
                                                 int* __restrict__ deg,
                                                 int* __restrict__ pos) {
    int e = blockIdx.x * 256 + threadIdx.x;
    if (e >= EE) return;
    pos[e] = atomicAdd(deg + dst[e], 1);
}

__device__ __forceinline__ int wave_incl_scan(int v, int lane) {
#pragma unroll
    for (int off = 1; off < 64; off <<= 1) {
        int t = __shfl_up(v, off, 64);
        if (lane >= off) v += t;
    }
    return v;
}

__global__ __launch_bounds__(256) void scan1(const int* __restrict__ deg,
                                             int* __restrict__ rowptr,
                                             int* __restrict__ bsum) {
    int tid = threadIdx.x, n = blockIdx.x * 256 + tid;
    int lane = tid & 63, wave = tid >> 6;
    int d = (n < NN) ? deg[n] : 0;
    int v = wave_incl_scan(d, lane);
    __shared__ int ws[4];
    if (lane == 63) ws[wave] = v;
    __syncthreads();
    int woff = 0;
    for (int w = 0; w < wave; ++w) woff += ws[w];
    int incl = v + woff;
    if (n < NN) rowptr[n] = incl - d;
    if (tid == 255) bsum[blockIdx.x] = incl;
}

__global__ __launch_bounds__(512) void scan2(const int* __restrict__ bsum,
                                             int* __restrict__ boff) {
    int t = threadIdx.x;
    int lane = t & 63, wave = t >> 6;
    int d = (t < NB_SCAN) ? bsum[t] : 0;
    int v = wave_incl_scan(d, lane);
    __shared__ int ws[8];
    if (lane == 63) ws[wave] = v;
    __syncthreads();
    int woff = 0;
    for (int w = 0; w < wave; ++w) woff += ws[w];
    if (t < NB_SCAN) boff[t] = v + woff - d;
}

__global__ __launch_bounds__(256) void scan3(int* __restrict__ rowptr,
                                             const int* __restrict__ boff) {
    int n = blockIdx.x * 256 + threadIdx.x;
    if (n == 0) rowptr[NN] = EE;
    if (n < NN) rowptr[n] += boff[blockIdx.x];
}

__global__ __launch_bounds__(256) void csr_scatter(const int* __restrict__ src,
                                                   const int* __restrict__ dst,
                                                   const int* __restrict__ rowptr,
                                                   const int* __restrict__ pos,
                                                   int* __restrict__ perm,
                                                   int* __restrict__ srcs) {
    int e = blockIdx.x * 256 + threadIdx.x;
    if (e >= EE) return;
    int p = rowptr[dst[e]] + pos[e];
    perm[e] = p;
    srcs[p] = src[e];
}

// ---------------------------------------------------------------------------
// a_s[n][h] = sum_c xh[n][h*64+c]*att_s[h*64+c]; same for a_d.
// ---------------------------------------------------------------------------
__global__ __launch_bounds__(256) void att_score(const __half* __restrict__ xh,
                                                 const float* __restrict__ as_,
                                                 const float* __restrict__ ad_,
                                                 float* __restrict__ a_s,
                                                 float* __restrict__ a_d) {
    const int lane = threadIdx.x & 63, wave = threadIdx.x >> 6;
    const int n = blockIdx.x * 4 + wave;
    const int c0 = lane * 4;

    float ws0 = as_[c0], ws1 = as_[c0 + 1], ws2 = as_[c0 + 2], ws3 = as_[c0 + 3];
    float wd0 = ad_[c0], wd1 = ad_[c0 + 1], wd2 = ad_[c0 + 2], wd3 = ad_[c0 + 3];

    const __half2* p = (const __half2*)(xh + (size_t)n * HC);
    __half2 v0 = p[lane * 2], v1 = p[lane * 2 + 1];
    float x0 = __low2float(v0), x1 = __high2float(v0);
    float x2 = __low2float(v1), x3 = __high2float(v1);

    float ss = x0 * ws0 + x1 * ws1 + x2 * ws2 + x3 * ws3;
    float dd = x0 * wd0 + x1 * wd1 + x2 * wd2 + x3 * wd3;
#pragma unroll
    for (int m = 8; m >= 1; m >>= 1) {
        ss += __shfl_xor(ss, m, 64);
        dd += __shfl_xor(dd, m, 64);
    }
    if ((lane & 15) == 0) {
        a_s[n * HEADS + (lane >> 4)] = ss;
        a_d[n * HEADS + (lane >> 4)] = dd;
    }
}

// ---------------------------------------------------------------------------
// Per (edge, head): ex = exp(leaky_relu(a_s[src]+a_d[dst])), written to the
// CSR-sorted slot (softmax shift-invariant; logits tiny -> no segment_max).
// ---------------------------------------------------------------------------
__global__ __launch_bounds__(256) void edge_score(const int* __restrict__ src,
                                                  const int* __restrict__ dst,
                                                  const int* __restrict__ perm,
                                                  const float* __restrict__ a_s,
                                                  const float* __restrict__ a_d,
                                                  float* __restrict__ exs) {
    int idx = blockIdx.x * 256 + threadIdx.x;
    if (idx >= EE * HEADS) return;
    int e = idx >> 2, h = idx & 3;
    int s = src[e], d = dst[e];
    float v = a_s[s * HEADS + h] + a_d[d * HEADS + h];
    v = (v > 0.f) ? v : v * NEG_SLOPE;
    exs[perm[e] * HEADS + h] = __expf(v);
}

// ---------------------------------------------------------------------------
// Gather-aggregate + fused BN/ReLU/residual. One wave per dst node, no
// atomics. Edge loop unrolled x4 with clamped indices + zero weights:
// always 4 independent 512B row-gathers in flight per wave (4x MLP vs the
// serial 1-in-flight loop that stalled at 2.7 TB/s).
// ---------------------------------------------------------------------------
__global__ __launch_bounds__(256) void gather_agg(const int* __restrict__ rowptr,
                                                  const int* __restrict__ srcs,
                                                  const float* __restrict__ exs,
                                                  const __half* __restrict__ xh,
                                                  const float* __restrict__ bg,
                                                  const float* __restrict__ g,
                                                  const float* __restrict__ be,
                                                  __half* __restrict__ h,
                                                  int residual) {
    const int n = blockIdx.x * 4 + (threadIdx.x >> 6);
    const int lane = threadIdx.x & 63;
    if (n >= NN) return;
    const int hd = lane >> 4;
    const int c0 = lane * 4;

    const int start = rowptr[n], end = rowptr[n + 1];
    float a0 = 0.f, a1 = 0.f, a2 = 0.f, a3 = 0.f, den = 0.f;

    const __half* xb = xh + c0;
    for (int i = start; i < end; i += 4) {
        // clamped indices: safe loads; weights forced to 0 past `end`
        const int j1 = (i + 1 < end) ? i + 1 : i;
        const int j2 = (i + 2 < end) ? i + 2 : i;
        const int j3 = (i + 3 < end) ? i + 3 : i;
        const int s0 = srcs[i], s1 = srcs[j1], s2 = srcs[j2], s3 = srcs[j3];

        float e0 = exs[i * HEADS + hd];
        float e1 = (i + 1 < end) ? exs[j1 * HEADS + hd] : 0.f;
        float e2 = (i + 2 < end) ? exs[j2 * HEADS + hd] : 0.f;
        float e3 = (i + 3 < end) ? exs[j3 * HEADS + hd] : 0.f;

        union { float2 f2; __half2 h2[2]; } u0, u1, u2, u3;
        u0.f2 = *(const float2*)(xb + (size_t)s0 * HC);
        u1.f2 = *(const float2*)(xb + (size_t)s1 * HC);
        u2.f2 = *(const float2*)(xb + (size_t)s2 * HC);
        u3.f2 = *(const float2*)(xb + (size_t)s3 * HC);

        a0 += e0 * __low2float(u0.h2[0])  + e1 * __low2float(u1.h2[0])
            + e2 * __low2float(u2.h2[0])  + e3 * __low2float(u3.h2[0]);
        a1 += e0 * __high2float(u0.h2[0]) + e1 * __high2float(u1.h2[0])
            + e2 * __high2float(u2.h2[0]) + e3 * __high2float(u3.h2[0]);
        a2 += e0 * __low2float(u0.h2[1])  + e1 * __low2float(u1.h2[1])
            + e2 * __low2float(u2.h2[1])  + e3 * __low2float(u3.h2[1]);
        a3 += e0 * __high2float(u0.h2[1]) + e1 * __high2float(u1.h2[1])
            + e2 * __high2float(u2.h2[1]) + e3 * __high2float(u3.h2[1]);
        den += e0 + e1 + e2 + e3;
    }
    float inv = 1.f / (den + 1e-16f);

    float r0 = fmaxf((a0 * inv + bg[c0])     * (g[c0]     * BN_SCALE) + be[c0],     0.f);
    float r1 = fmaxf((a1 * inv + bg[c0 + 1]) * (g[c0 + 1] * BN_SCALE) + be[c0 + 1], 0.f);
    float r2 = fmaxf((a2 * inv + bg[c0 + 2]) * (g[c0 + 2] * BN_SCALE) + be[c0 + 2], 0.f);
    float r3 = fmaxf((a3 * inv + bg[c0 + 3]) * (g[c0 + 3] * BN_SCALE) + be[c0 + 3], 0.f);

    __half2* hp = (__half2*)(h + (size_t)n * HC + c0);
    if (residual) {
        __half2 o0 = hp[0], o1 = hp[1];
        r0 += __low2float(o0); r1 += __high2float(o0);
        r2 += __low2float(o1); r3 += __high2float(o1);
    }
    hp[0] = __floats2half2_rn(r0, r1);
    hp[1] = __floats2half2_rn(r2, r3);
}

// ---------------------------------------------------------------------------
// Final fused edge MLP:
// Phase 1: per block, 64 edges; MFMA computes z_pre = ea@W1e + b1 into LDS.
// Phase 2: 4 threads/edge gather hs[src], hd[dst], ReLU, dot(W2), reduce.
// ---------------------------------------------------------------------------
__global__ __launch_bounds__(256) void edge_final(const float* __restrict__ ea,
                                                  const __half* __restrict__ w1et,
                                                  const float* __restrict__ b1,
                                                  const int* __restrict__ src,
                                                  const int* __restrict__ dst,
                                                  const __half* __restrict__ hshd,
                                                  const float* __restrict__ W2,
                                                  const float* __restrict__ b2,
                                                  float* __restrict__ out) {
    __shared__ float zl[64][36];   // stride 36: 16B-aligned rows, <=2-way banks
    const int wave = threadIdx.x >> 6, lane = threadIdx.x & 63;
    const int e0 = blockIdx.x * 64;
    const int lrow = lane & 15, kofs = (lane >> 4) * 8;

    // ---- Phase 1: MFMA z = ea @ W1e (K=32), 16 edges per wave ----
    int er = e0 + wave * 16 + lrow;
    if (er >= EE) er = EE - 1;
    const float* ap = ea + (size_t)er * F_EDGE + kofs;
    float4 f0 = *(const float4*)ap;
    float4 f1 = *(const float4*)(ap + 4);
    half8 a;
    a[0] = (_Float16)f0.x; a[1] = (_Float16)f0.y;
    a[2] = (_Float16)f0.z; a[3] = (_Float16)f0.w;
    a[4] = (_Float16)f1.x; a[5] = (_Float16)f1.y;
    a[6] = (_Float16)f1.z; a[7] = (_Float16)f1.w;

    half8 b0 = *(const half8*)(w1et + (size_t)lrow * 32 + kofs);
    half8 b1v = *(const half8*)(w1et + (size_t)(16 + lrow) * 32 + kofs);
    f32x4 acc0 = {}, acc1 = {};
    acc0 = __builtin_amdgcn_mfma_f32_16x16x32_f16(a, b0,  acc0, 0, 0, 0);
    acc1 = __builtin_amdgcn_mfma_f32_16x16x32_f16(a, b1v, acc1, 0, 0, 0);

    const int crow = (lane >> 4) * 4;
    const float bc0 = b1[lrow], bc1 = b1[16 + lrow];
#pragma unroll
    for (int r = 0; r < 4; ++r) {
        zl[wave * 16 + crow + r][lrow]      = acc0[r] + bc0;
        zl[wave * 16 + crow + r][16 + lrow] = acc1[r] + bc1;
    }
    __syncthreads();

    // ---- Phase 2: gather + ReLU + dot(W2) ----
    const int el = threadIdx.x >> 2, j0 = (threadIdx.x & 3) * 8;
    const int e = e0 + el;
    const bool ok = e < EE;
    const int s = ok ? src[e] : 0;
    const int d = ok ? dst[e] : 0;

    half8 hs = *(const half8*)(hshd + (size_t)s * 64 + j0);
    half8 hdv = *(const half8*)(hshd + (size_t)d * 64 + 32 + j0);
    float w2v[8];
    *(float4*)(w2v)     = *(const float4*)(W2 + j0);
    *(float4*)(w2v + 4) = *(const float4*)(W2 + j0 + 4);
    float4 z0 = *(const float4*)&zl[el][j0];
    float4 z1 = *(const float4*)&zl[el][j0 + 4];

    float acc = 0.f;
    const float* zp0 = &z0.x;
    const float* zp1 = &z1.x;
#pragma unroll
    for (int i = 0; i < 4; ++i) {
        float z = zp0[i] + (float)hs[i] + (float)hdv[i];
        acc += fmaxf(z, 0.f) * w2v[i];
    }
#pragma unroll
    for (int i = 0; i < 4; ++i) {
        float z = zp1[i] + (float)hs[4 + i] + (float)hdv[4 + i];
        acc += fmaxf(z, 0.f) * w2v[4 + i];
    }
    acc += __shfl_xor(acc, 1, 64);
    acc += __shfl_xor(acc, 2, 64);
    if (ok && (threadIdx.x & 3) == 0) out[e] = acc + b2[0];
}

// ---------------------------------------------------------------------------
extern "C" void kernel_launch(void* const* d_in, const int* in_sizes, int n_in,
                              void* d_out, int out_size, void* d_ws, size_t ws_size,
                              hipStream_t stream) {
    const float* x  = (const float*)d_in[0];
    const int*   ei = (const int*)d_in[1];
    const float* ea = (const float*)d_in[2];
    const float* Wp = (const float*)d_in[3];
    const float* bp = (const float*)d_in[4];
    const float* W1 = (const float*)d_in[23];
    const float* b1 = (const float*)d_in[24];
    const float* W2 = (const float*)d_in[25];
    const float* b2 = (const float*)d_in[26];
    const int* src = ei;
    const int* dst = ei + EE;

    // Workspace layout (float offsets). All matrix buffers padded to MPAD
    // rows so the 782-block (128-row) GEMM grid needs no bounds checks.
    float* ws = (float*)d_ws;
    __half* h      = (__half*)(ws);               // MPAD*256 halfs
    __half* xh     = (__half*)(ws + 12820000);    // MPAD*256 halfs
    __half* x16    = (__half*)(ws + 25640000);    // MPAD*128 halfs
    __half* h0     = (__half*)(ws + 32050000);    // MPAD*64 halfs
    __half* hshd   = (__half*)(ws + 35260000);    // MPAD*64 halfs
    float*  a_s    = ws + 38470000;               // NN*4
    float*  a_d    = ws + 38870000;               // NN*4
    float*  exs    = ws + 39270000;               // EE*4
    int*    rowptr = (int*)(ws + 41270000);       // NN+1
    int*    deg    = (int*)(ws + 41380000);       // NN
    int*    pos    = (int*)(ws + 41480000);       // EE
    int*    perm   = (int*)(ws + 41990000);       // EE
    int*    srcs   = (int*)(ws + 42490000);       // EE
    int*    bsum   = (int*)(ws + 42990000);       // NB_SCAN
    int*    boff   = (int*)(ws + 42991000);       // NB_SCAN
    __half* wpt    = (__half*)(ws + 42992000);    // 64x128 (reused as w1et)
    __half* wgt    = (__half*)(ws + 43000000);    // 256x256
    __half* w1t    = (__half*)(ws + 43020000);    // 64x256
    float*  out    = (float*)d_out;

    const int MB = MPAD / 128;   // 782 row-blocks

    // ---- CSR build (once) ----
    hipMemsetAsync(deg, 0, (size_t)NN * sizeof(int), stream);
    csr_count<<<(EE + 255) / 256, 256, 0, stream>>>(dst, deg, pos);
    scan1<<<NB_SCAN, 256, 0, stream>>>(deg, rowptr, bsum);
    scan2<<<1, 512, 0, stream>>>(bsum, boff);
    scan3<<<NB_SCAN, 256, 0, stream>>>(rowptr, boff);
    csr_scatter<<<(EE + 255) / 256, 256, 0, stream>>>(src, dst, rowptr, pos, perm, srcs);

    // ---- prep: x->fp16, Wp^T ----
    cvt_x<<<NN * F_NODE / 4 / 256, 256, 0, stream>>>(x, x16);
    wt_conv<<<(F_NODE * 64 + 255) / 256, 256, 0, stream>>>(Wp, wpt, F_NODE, 64);

    // h0 = relu(x @ Wp + bp)
    mgemm2<F_NODE, 64, 1><<<dim3(MB, 1), 256, 0, stream>>>(x16, wpt, bp, h0);

    for (int l = 0; l < 3; ++l) {
        const float* Wg  = (const float*)d_in[5 + 6 * l];
        const float* as_ = (const float*)d_in[6 + 6 * l];
        const float* ad_ = (const float*)d_in[7 + 6 * l];
        const float* bg  = (const float*)d_in[8 + 6 * l];
        const float* g   = (const float*)d_in[9 + 6 * l];
        const float* be  = (const float*)d_in[10 + 6 * l];

        if (l == 0) {
            wt_conv<<<(CC * HC + 255) / 256, 256, 0, stream>>>(Wg, wgt, CC, HC);
            mgemm2<CC, HC, 0><<<dim3(MB, 2), 256, 0, stream>>>(h0, wgt, nullptr, xh);
        } else {
            wt_conv<<<(HC * HC + 255) / 256, 256, 0, stream>>>(Wg, wgt, HC, HC);
            mgemm2<HC, HC, 0><<<dim3(MB, 2), 256, 0, stream>>>(h, wgt, nullptr, xh);
        }

        att_score<<<NN / 4, 256, 0, stream>>>(xh, as_, ad_, a_s, a_d);
        edge_score<<<(EE * HEADS + 255) / 256, 256, 0, stream>>>(src, dst, perm, a_s, a_d, exs);
        gather_agg<<<(NN + 3) / 4, 256, 0, stream>>>(rowptr, srcs, exs, xh, bg, g, be, h, l > 0 ? 1 : 0);
    }

    // hs|hd = h @ [W1s | W1d]
    wt_final<<<(64 * 256 + 255) / 256, 256, 0, stream>>>(W1, w1t);
    mgemm2<HC, 64, 0><<<dim3(MB, 1), 256, 0, stream>>>(h, w1t, nullptr, hshd);

    // W1e^T -> fp16 (reuse wpt; first mgemm2 that used it is long done)
    wt_conv<<<(32 * 32 + 255) / 256, 256, 0, stream>>>(W1 + 2 * HC * OUTD, wpt, 32, 32);
    edge_final<<<(EE + 63) / 64, 256, 0, stream>>>(ea, wpt, b1, src, dst, hshd, W2, b2, out);
}

// Round 4
// 409.434 us; speedup vs baseline: 1.7254x; 1.0940x over previous
//
#include <hip/hip_runtime.h>
#include <hip/hip_fp16.h>

// Problem constants
#define NN 100000
#define EE 500000
#define F_NODE 128
#define F_EDGE 32
#define HEADS 4
#define CC 64
#define HC 256
#define OUTD 32
#define NEG_SLOPE 0.2f
#define BN_SCALE 0.9999950000374997f   // 1/sqrt(1+1e-5)
#define NB_SCAN 391                    // ceil(NN/256)
#define MPAD 100096                    // NN padded to multiple of 128

using half8 = __attribute__((ext_vector_type(8))) _Float16;
using f32x4 = __attribute__((ext_vector_type(4))) float;

typedef const __attribute__((address_space(1))) void* gas_ptr;
typedef __attribute__((address_space(3))) void* las_ptr;

// ---------------------------------------------------------------------------
// Tiled MFMA GEMM: C[m][n] = sum_k A[m][k] * Wt[n][k]
//   A fp16 [M][K] row-major (M padded to >= grid*128 rows, garbage pad ok)
//   Wt fp16 [NOUT][K] row-major (weights pre-transposed)
//   C fp16 [M][NOUT] (padded; pad rows receive garbage, never read)
// Tile: BM=128 x BN=(128 or 64), BK=64. 4 waves in 2x2; each wave owns
// 64 x (BN/2) output = MIxNI 16x16 fragments.
// LDS: double-buffered A[128][64] + B[BN][64] fp16, linear dest via
// global_load_lds(16B), XOR-swizzled SOURCE (unit ^= row&7) and the same
// XOR applied on ds_read_b128 -> 2-way banks (free) instead of 16-way.
// One barrier per K-step, stage-ahead prefetch (m97 2-phase structure).
// MODE 1: + bias[col], ReLU.
// ---------------------------------------------------------------------------
template<int K, int NOUT, int MODE>
__global__ __launch_bounds__(256, 2) void mgemm2(const __half* __restrict__ A,
                                                 const __half* __restrict__ Wt,
                                                 const float* __restrict__ bias,
                                                 __half* __restrict__ C) {
    constexpr int BM = 128;
    constexpr int BN = (NOUT >= 128) ? 128 : 64;
    constexpr int MI = 4;
    constexpr int NI = BN / 32;
    constexpr int KS = K / 64;
    constexpr int ABYTES = BM * 128;   // 128 rows x 64 halfs
    constexpr int BBYTES = BN * 128;
    __shared__ char smem[2 * (ABYTES + BBYTES)];

    const int tid  = threadIdx.x;
    const int wave = tid >> 6, lane = tid & 63;
    const int wr = wave >> 1, wc = wave & 1;
    const int lrow = lane & 15, kq = lane >> 4;
    const int m0 = blockIdx.x * BM;
    const int n0 = blockIdx.y * BN;
    const int srow = tid >> 3;         // 0..31 staging row within 32-row slab
    const int sunit = tid & 7;         // physical 16B unit within row
    const int wofs = (tid & 192) * 16; // wave-uniform LDS offset (w*1024)

    // stage one BK=64 tile of A and B into buffer `buf`
    auto stage = [&](int buf, int ks) {
        char* base = smem + buf * (ABYTES + BBYTES);
        const int kk = ks * 64;
#pragma unroll
        for (int it = 0; it < BM / 32; ++it) {
            const int r = srow + it * 32;
            const __half* src = A + (size_t)(m0 + r) * K + kk + ((sunit ^ (r & 7)) << 3);
            __builtin_amdgcn_global_load_lds((gas_ptr)src,
                (las_ptr)(base + it * 4096 + wofs), 16, 0, 0);
        }
#pragma unroll
        for (int it = 0; it < BN / 32; ++it) {
            const int r = srow + it * 32;
            const __half* src = Wt + (size_t)(n0 + r) * K + kk + ((sunit ^ (r & 7)) << 3);
            __builtin_amdgcn_global_load_lds((gas_ptr)src,
                (las_ptr)(base + ABYTES + it * 4096 + wofs), 16, 0, 0);
        }
    };

    f32x4 acc[MI][NI] = {};

    auto compute = [&](int buf) {
        const char* Ab = smem + buf * (ABYTES + BBYTES);
        const char* Bb = Ab + ABYTES;
#pragma unroll
        for (int k32 = 0; k32 < 2; ++k32) {
            const int ku = k32 * 4 + kq;       // logical 16B unit (0..7)
            half8 af[MI], bf[NI];
#pragma unroll
            for (int mi = 0; mi < MI; ++mi) {
                const int rr = wr * 64 + mi * 16 + lrow;
                af[mi] = *(const half8*)(Ab + rr * 128 + ((ku ^ (rr & 7)) << 4));
            }
#pragma unroll
            for (int ni = 0; ni < NI; ++ni) {
                const int rc = wc * (BN / 2) + ni * 16 + lrow;
                bf[ni] = *(const half8*)(Bb + rc * 128 + ((ku ^ (rc & 7)) << 4));
            }
#pragma unroll
            for (int mi = 0; mi < MI; ++mi)
#pragma unroll
                for (int ni = 0; ni < NI; ++ni)
                    acc[mi][ni] = __builtin_amdgcn_mfma_f32_16x16x32_f16(
                        af[mi], bf[ni], acc[mi][ni], 0, 0, 0);
        }
    };

    stage(0, 0);
    __syncthreads();                    // drain prologue stage
    int cur = 0;
#pragma unroll
    for (int ks = 0; ks < KS; ++ks) {
        if (ks + 1 < KS) stage(cur ^ 1, ks + 1);
        compute(cur);
        __syncthreads();                // drains next stage + guards re-stage
        cur ^= 1;
    }

    const int crow = kq * 4;
#pragma unroll
    for (int mi = 0; mi < MI; ++mi) {
#pragma unroll
        for (int ni = 0; ni < NI; ++ni) {
            const int col = n0 + wc * (BN / 2) + ni * 16 + lrow;
            float bcol = (MODE == 1) ? bias[col] : 0.f;
#pragma unroll
            for (int r = 0; r < 4; ++r) {
                float v = acc[mi][ni][r];
                if constexpr (MODE == 1) v = fmaxf(v + bcol, 0.f);
                const int row = m0 + wr * 64 + mi * 16 + crow + r;
                C[(size_t)row * NOUT + col] = __float2half(v);
            }
        }
    }
}

// ---------------------------------------------------------------------------
// Prep kernels: transpose-convert weights to fp16 NxK, cast x to fp16.
// ---------------------------------------------------------------------------
__global__ __launch_bounds__(256) void wt_conv(const float* __restrict__ W,
                                               __half* __restrict__ Wt,
                                               int K, int N) {
    int idx = blockIdx.x * 256 + threadIdx.x;   // over N*K, output-contiguous
    if (idx >= K * N) return;
    int n = idx / K, k = idx % K;
    Wt[idx] = __float2half(W[k * N + n]);
}

// Wt_final[n][k]: n<32 -> W1[k][n] (W1s), n>=32 -> W1[256+k][n-32] (W1d)
__global__ __launch_bounds__(256) void wt_final(const float* __restrict__ W1,
                                                __half* __restrict__ Wt) {
    int idx = blockIdx.x * 256 + threadIdx.x;   // over 64*256
    if (idx >= 64 * 256) return;
    int n = idx >> 8, k = idx & 255;
    float v = (n < 32) ? W1[k * 32 + n] : W1[(256 + k) * 32 + (n - 32)];
    Wt[idx] = __float2half(v);
}

__global__ __launch_bounds__(256) void cvt_x(const float* __restrict__ x,
                                             __half* __restrict__ x16) {
    int i = blockIdx.x * 256 + threadIdx.x;     // over NN*F_NODE/4
    float4 v = ((const float4*)x)[i];
    __half2* o = (__half2*)x16 + (size_t)i * 2;
    o[0] = __floats2half2_rn(v.x, v.y);
    o[1] = __floats2half2_rn(v.z, v.w);
}

// ---------------------------------------------------------------------------
// CSR build: deg-count, two-level exclusive scan, scatter.
// ---------------------------------------------------------------------------
__global__ __launch_bounds__(256) void csr_count(const int* __restrict__ dst,
                                                 int* __restrict__ deg,
                                                 int* __restrict__ pos) {
    int e = blockIdx.x * 256 + threadIdx.x;
    if (e >= EE) return;
    pos[e] = atomicAdd(deg + dst[e], 1);
}

__device__ __forceinline__ int wave_incl_scan(int v, int lane) {
#pragma unroll
    for (int off = 1; off < 64; off <<= 1) {
        int t = __shfl_up(v, off, 64);
        if (lane >= off) v += t;
    }
    return v;
}

__global__ __launch_bounds__(256) void scan1(const int* __restrict__ deg,
                                             int* __restrict__ rowptr,
                                             int* __restrict__ bsum) {
    int tid = threadIdx.x, n = blockIdx.x * 256 + tid;
    int lane = tid & 63, wave = tid >> 6;
    int d = (n < NN) ? deg[n] : 0;
    int v = wave_incl_scan(d, lane);
    __shared__ int ws[4];
    if (lane == 63) ws[wave] = v;
    __syncthreads();
    int woff = 0;
    for (int w = 0; w < wave; ++w) woff += ws[w];
    int incl = v + woff;
    if (n < NN) rowptr[n] = incl - d;
    if (tid == 255) bsum[blockIdx.x] = incl;
}

__global__ __launch_bounds__(512) void scan2(const int* __restrict__ bsum,
                                             int* __restrict__ boff) {
    int t = threadIdx.x;
    int lane = t & 63, wave = t >> 6;
    int d = (t < NB_SCAN) ? bsum[t] : 0;
    int v = wave_incl_scan(d, lane);
    __shared__ int ws[8];
    if (lane == 63) ws[wave] = v;
    __syncthreads();
    int woff = 0;
    for (int w = 0; w < wave; ++w) woff += ws[w];
    if (t < NB_SCAN) boff[t] = v + woff - d;
}

__global__ __launch_bounds__(256) void scan3(int* __restrict__ rowptr,
                                             const int* __restrict__ boff) {
    int n = blockIdx.x * 256 + threadIdx.x;
    if (n == 0) rowptr[NN] = EE;
    if (n < NN) rowptr[n] += boff[blockIdx.x];
}

__global__ __launch_bounds__(256) void csr_scatter(const int* __restrict__ src,
                                                   const int* __restrict__ dst,
                                                   const int* __restrict__ rowptr,
                                                   const int* __restrict__ pos,
                                                   int* __restrict__ srcs) {
    int e = blockIdx.x * 256 + threadIdx.x;
    if (e >= EE) return;
    srcs[rowptr[dst[e]] + pos[e]] = src[e];
}

// ---------------------------------------------------------------------------
// a_s[n][h] = sum_c xh[n][h*64+c]*att_s[h*64+c]; same for a_d.
// ---------------------------------------------------------------------------
__global__ __launch_bounds__(256) void att_score(const __half* __restrict__ xh,
                                                 const float* __restrict__ as_,
                                                 const float* __restrict__ ad_,
                                                 float* __restrict__ a_s,
                                                 float* __restrict__ a_d) {
    const int lane = threadIdx.x & 63, wave = threadIdx.x >> 6;
    const int n = blockIdx.x * 4 + wave;
    const int c0 = lane * 4;

    float ws0 = as_[c0], ws1 = as_[c0 + 1], ws2 = as_[c0 + 2], ws3 = as_[c0 + 3];
    float wd0 = ad_[c0], wd1 = ad_[c0 + 1], wd2 = ad_[c0 + 2], wd3 = ad_[c0 + 3];

    const __half2* p = (const __half2*)(xh + (size_t)n * HC);
    __half2 v0 = p[lane * 2], v1 = p[lane * 2 + 1];
    float x0 = __low2float(v0), x1 = __high2float(v0);
    float x2 = __low2float(v1), x3 = __high2float(v1);

    float ss = x0 * ws0 + x1 * ws1 + x2 * ws2 + x3 * ws3;
    float dd = x0 * wd0 + x1 * wd1 + x2 * wd2 + x3 * wd3;
#pragma unroll
    for (int m = 8; m >= 1; m >>= 1) {
        ss += __shfl_xor(ss, m, 64);
        dd += __shfl_xor(dd, m, 64);
    }
    if ((lane & 15) == 0) {
        a_s[n * HEADS + (lane >> 4)] = ss;
        a_d[n * HEADS + (lane >> 4)] = dd;
    }
}

// ---------------------------------------------------------------------------
// Gather-aggregate with FUSED edge scoring + BN/ReLU/residual.
// One wave per dst node; each HALF-wave (32 lanes) owns one edge slot with
// 16B half8 loads -> one load instr fetches 2 rows; x4 unroll per half =
// 8 rows in flight per wave. Score ex = exp(lrelu(a_s[src]+a_d[n])) computed
// inline (a_s is 1.6MB -> L2-resident gather); no exs/perm round-trip.
// ---------------------------------------------------------------------------
__global__ __launch_bounds__(256) void gather_agg(const int* __restrict__ rowptr,
                                                  const int* __restrict__ srcs,
                                                  const float* __restrict__ a_s,
                                                  const float* __restrict__ a_d,
                                                  const __half* __restrict__ xh,
                                                  const float* __restrict__ bg,
                                                  const float* __restrict__ g,
                                                  const float* __restrict__ be,
                                                  __half* __restrict__ h,
                                                  int residual) {
    const int n = blockIdx.x * 4 + (threadIdx.x >> 6);
    const int lane = threadIdx.x & 63;
    if (n >= NN) return;
    const int hl = lane >> 5;          // half-wave: edge-slot parity
    const int l5 = lane & 31;
    const int hd = l5 >> 3;            // head of my 8 cols
    const int c0 = l5 * 8;             // col base (16B aligned)

    const int start = rowptr[n], end = rowptr[n + 1];
    const float adv = a_d[n * HEADS + hd];

    float acc[8] = {};
    float den = 0.f;

    for (int i = start + hl; i < end; i += 8) {
        // 4 slots per half: i, i+2, i+4, i+6 (clamped; zero weight past end)
        int  j0 = i,                 j1 = (i + 2 < end) ? i + 2 : i;
        int  j2 = (i + 4 < end) ? i + 4 : i;
        int  j3 = (i + 6 < end) ? i + 6 : i;
        const int s0 = srcs[j0], s1 = srcs[j1], s2 = srcs[j2], s3 = srcs[j3];

        float v0 = a_s[s0 * HEADS + hd] + adv;
        float v1 = a_s[s1 * HEADS + hd] + adv;
        float v2 = a_s[s2 * HEADS + hd] + adv;
        float v3 = a_s[s3 * HEADS + hd] + adv;
        v0 = (v0 > 0.f) ? v0 : v0 * NEG_SLOPE;
        v1 = (v1 > 0.f) ? v1 : v1 * NEG_SLOPE;
        v2 = (v2 > 0.f) ? v2 : v2 * NEG_SLOPE;
        v3 = (v3 > 0.f) ? v3 : v3 * NEG_SLOPE;
        float e0 = __expf(v0);
        float e1 = (i + 2 < end) ? __expf(v1) : 0.f;
        float e2 = (i + 4 < end) ? __expf(v2) : 0.f;
        float e3 = (i + 6 < end) ? __expf(v3) : 0.f;

        half8 r0 = *(const half8*)(xh + (size_t)s0 * HC + c0);
        half8 r1 = *(const half8*)(xh + (size_t)s1 * HC + c0);
        half8 r2 = *(const half8*)(xh + (size_t)s2 * HC + c0);
        half8 r3 = *(const half8*)(xh + (size_t)s3 * HC + c0);

#pragma unroll
        for (int k = 0; k < 8; ++k)
            acc[k] += e0 * (float)r0[k] + e1 * (float)r1[k]
                    + e2 * (float)r2[k] + e3 * (float)r3[k];
        den += e0 + e1 + e2 + e3;
    }

    // combine the two half-waves (same node, disjoint edge subsets)
    den += __shfl_xor(den, 32, 64);
#pragma unroll
    for (int k = 0; k < 8; ++k) acc[k] += __shfl_xor(acc[k], 32, 64);

    if (hl != 0) return;               // half 0 holds full sums; writes row
    const float inv = 1.f / (den + 1e-16f);

    float bgv[8], gv[8], bev[8];
    *(float4*)(bgv)     = *(const float4*)(bg + c0);
    *(float4*)(bgv + 4) = *(const float4*)(bg + c0 + 4);
    *(float4*)(gv)      = *(const float4*)(g + c0);
    *(float4*)(gv + 4)  = *(const float4*)(g + c0 + 4);
    *(float4*)(bev)     = *(const float4*)(be + c0);
    *(float4*)(bev + 4) = *(const float4*)(be + c0 + 4);

    half8* hp = (half8*)(h + (size_t)n * HC + c0);
    float r[8];
#pragma unroll
    for (int k = 0; k < 8; ++k)
        r[k] = fmaxf((acc[k] * inv + bgv[k]) * (gv[k] * BN_SCALE) + bev[k], 0.f);
    if (residual) {
        half8 old = *hp;
#pragma unroll
        for (int k = 0; k < 8; ++k) r[k] += (float)old[k];
    }
    half8 o;
#pragma unroll
    for (int k = 0; k < 8; ++k) o[k] = (_Float16)r[k];
    *hp = o;
}

// ---------------------------------------------------------------------------
// Final fused edge MLP:
// Phase 1: per block, 64 edges; MFMA computes z_pre = ea@W1e + b1 into LDS.
// Phase 2: 4 threads/edge gather hs[src], hd[dst], ReLU, dot(W2), reduce.
// ---------------------------------------------------------------------------
__global__ __launch_bounds__(256) void edge_final(const float* __restrict__ ea,
                                                  const __half* __restrict__ w1et,
                                                  const float* __restrict__ b1,
                                                  const int* __restrict__ src,
                                                  const int* __restrict__ dst,
                                                  const __half* __restrict__ hshd,
                                                  const float* __restrict__ W2,
                                                  const float* __restrict__ b2,
                                                  float* __restrict__ out) {
    __shared__ float zl[64][36];   // stride 36: 16B-aligned rows, <=2-way banks
    const int wave = threadIdx.x >> 6, lane = threadIdx.x & 63;
    const int e0 = blockIdx.x * 64;
    const int lrow = lane & 15, kofs = (lane >> 4) * 8;

    // ---- Phase 1: MFMA z = ea @ W1e (K=32), 16 edges per wave ----
    int er = e0 + wave * 16 + lrow;
    if (er >= EE) er = EE - 1;
    const float* ap = ea + (size_t)er * F_EDGE + kofs;
    float4 f0 = *(const float4*)ap;
    float4 f1 = *(const float4*)(ap + 4);
    half8 a;
    a[0] = (_Float16)f0.x; a[1] = (_Float16)f0.y;
    a[2] = (_Float16)f0.z; a[3] = (_Float16)f0.w;
    a[4] = (_Float16)f1.x; a[5] = (_Float16)f1.y;
    a[6] = (_Float16)f1.z; a[7] = (_Float16)f1.w;

    half8 b0 = *(const half8*)(w1et + (size_t)lrow * 32 + kofs);
    half8 b1v = *(const half8*)(w1et + (size_t)(16 + lrow) * 32 + kofs);
    f32x4 acc0 = {}, acc1 = {};
    acc0 = __builtin_amdgcn_mfma_f32_16x16x32_f16(a, b0,  acc0, 0, 0, 0);
    acc1 = __builtin_amdgcn_mfma_f32_16x16x32_f16(a, b1v, acc1, 0, 0, 0);

    const int crow = (lane >> 4) * 4;
    const float bc0 = b1[lrow], bc1 = b1[16 + lrow];
#pragma unroll
    for (int r = 0; r < 4; ++r) {
        zl[wave * 16 + crow + r][lrow]      = acc0[r] + bc0;
        zl[wave * 16 + crow + r][16 + lrow] = acc1[r] + bc1;
    }
    __syncthreads();

    // ---- Phase 2: gather + ReLU + dot(W2) ----
    const int el = threadIdx.x >> 2, j0 = (threadIdx.x & 3) * 8;
    const int e = e0 + el;
    const bool ok = e < EE;
    const int s = ok ? src[e] : 0;
    const int d = ok ? dst[e] : 0;

    half8 hs = *(const half8*)(hshd + (size_t)s * 64 + j0);
    half8 hdv = *(const half8*)(hshd + (size_t)d * 64 + 32 + j0);
    float w2v[8];
    *(float4*)(w2v)     = *(const float4*)(W2 + j0);
    *(float4*)(w2v + 4) = *(const float4*)(W2 + j0 + 4);
    float4 z0 = *(const float4*)&zl[el][j0];
    float4 z1 = *(const float4*)&zl[el][j0 + 4];

    float acc = 0.f;
    const float* zp0 = &z0.x;
    const float* zp1 = &z1.x;
#pragma unroll
    for (int i = 0; i < 4; ++i) {
        float z = zp0[i] + (float)hs[i] + (float)hdv[i];
        acc += fmaxf(z, 0.f) * w2v[i];
    }
#pragma unroll
    for (int i = 0; i < 4; ++i) {
        float z = zp1[i] + (float)hs[4 + i] + (float)hdv[4 + i];
        acc += fmaxf(z, 0.f) * w2v[4 + i];
    }
    acc += __shfl_xor(acc, 1, 64);
    acc += __shfl_xor(acc, 2, 64);
    if (ok && (threadIdx.x & 3) == 0) out[e] = acc + b2[0];
}

// ---------------------------------------------------------------------------
extern "C" void kernel_launch(void* const* d_in, const int* in_sizes, int n_in,
                              void* d_out, int out_size, void* d_ws, size_t ws_size,
                              hipStream_t stream) {
    const float* x  = (const float*)d_in[0];
    const int*   ei = (const int*)d_in[1];
    const float* ea = (const float*)d_in[2];
    const float* Wp = (const float*)d_in[3];
    const float* bp = (const float*)d_in[4];
    const float* W1 = (const float*)d_in[23];
    const float* b1 = (const float*)d_in[24];
    const float* W2 = (const float*)d_in[25];
    const float* b2 = (const float*)d_in[26];
    const int* src = ei;
    const int* dst = ei + EE;

    // Workspace layout (float offsets). All matrix buffers padded to MPAD
    // rows so the 782-block (128-row) GEMM grid needs no bounds checks.
    float* ws = (float*)d_ws;
    __half* h      = (__half*)(ws);               // MPAD*256 halfs
    __half* xh     = (__half*)(ws + 12820000);    // MPAD*256 halfs
    __half* x16    = (__half*)(ws + 25640000);    // MPAD*128 halfs
    __half* h0     = (__half*)(ws + 32050000);    // MPAD*64 halfs
    __half* hshd   = (__half*)(ws + 35260000);    // MPAD*64 halfs
    float*  a_s    = ws + 38470000;               // NN*4
    float*  a_d    = ws + 38870000;               // NN*4
    int*    rowptr = (int*)(ws + 41270000);       // NN+1
    int*    deg    = (int*)(ws + 41380000);       // NN
    int*    pos    = (int*)(ws + 41480000);       // EE
    int*    srcs   = (int*)(ws + 42490000);       // EE
    int*    bsum   = (int*)(ws + 42990000);       // NB_SCAN
    int*    boff   = (int*)(ws + 42991000);       // NB_SCAN
    __half* wpt    = (__half*)(ws + 42992000);    // 64x128 (reused as w1et)
    __half* wgt    = (__half*)(ws + 43000000);    // 256x256
    __half* w1t    = (__half*)(ws + 43020000);    // 64x256
    float*  out    = (float*)d_out;

    const int MB = MPAD / 128;   // 782 row-blocks

    // ---- CSR build (once) ----
    hipMemsetAsync(deg, 0, (size_t)NN * sizeof(int), stream);
    csr_count<<<(EE + 255) / 256, 256, 0, stream>>>(dst, deg, pos);
    scan1<<<NB_SCAN, 256, 0, stream>>>(deg, rowptr, bsum);
    scan2<<<1, 512, 0, stream>>>(bsum, boff);
    scan3<<<NB_SCAN, 256, 0, stream>>>(rowptr, boff);
    csr_scatter<<<(EE + 255) / 256, 256, 0, stream>>>(src, dst, rowptr, pos, srcs);

    // ---- prep: x->fp16, Wp^T ----
    cvt_x<<<NN * F_NODE / 4 / 256, 256, 0, stream>>>(x, x16);
    wt_conv<<<(F_NODE * 64 + 255) / 256, 256, 0, stream>>>(Wp, wpt, F_NODE, 64);

    // h0 = relu(x @ Wp + bp)
    mgemm2<F_NODE, 64, 1><<<dim3(MB, 1), 256, 0, stream>>>(x16, wpt, bp, h0);

    for (int l = 0; l < 3; ++l) {
        const float* Wg  = (const float*)d_in[5 + 6 * l];
        const float* as_ = (const float*)d_in[6 + 6 * l];
        const float* ad_ = (const float*)d_in[7 + 6 * l];
        const float* bg  = (const float*)d_in[8 + 6 * l];
        const float* g   = (const float*)d_in[9 + 6 * l];
        const float* be  = (const float*)d_in[10 + 6 * l];

        if (l == 0) {
            wt_conv<<<(CC * HC + 255) / 256, 256, 0, stream>>>(Wg, wgt, CC, HC);
            mgemm2<CC, HC, 0><<<dim3(MB, 2), 256, 0, stream>>>(h0, wgt, nullptr, xh);
        } else {
            wt_conv<<<(HC * HC + 255) / 256, 256, 0, stream>>>(Wg, wgt, HC, HC);
            mgemm2<HC, HC, 0><<<dim3(MB, 2), 256, 0, stream>>>(h, wgt, nullptr, xh);
        }

        att_score<<<NN / 4, 256, 0, stream>>>(xh, as_, ad_, a_s, a_d);
        gather_agg<<<(NN + 3) / 4, 256, 0, stream>>>(rowptr, srcs, a_s, a_d, xh,
                                                     bg, g, be, h, l > 0 ? 1 : 0);
    }

    // hs|hd = h @ [W1s | W1d]
    wt_final<<<(64 * 256 + 255) / 256, 256, 0, stream>>>(W1, w1t);
    mgemm2<HC, 64, 0><<<dim3(MB, 1), 256, 0, stream>>>(h, w1t, nullptr, hshd);

    // W1e^T -> fp16 (reuse wpt; first mgemm2 that used it is long done)
    wt_conv<<<(32 * 32 + 255) / 256, 256, 0, stream>>>(W1 + 2 * HC * OUTD, wpt, 32, 32);
    edge_final<<<(EE + 63) / 64, 256, 0, stream>>>(ea, wpt, b1, src, dst, hshd, W2, b2, out);
}

// Round 5
// 393.772 us; speedup vs baseline: 1.7940x; 1.0398x over previous
//
#include <hip/hip_runtime.h>
#include <hip/hip_fp16.h>

// Problem constants
#define NN 100000
#define EE 500000
#define F_NODE 128
#define F_EDGE 32
#define HEADS 4
#define CC 64
#define HC 256
#define OUTD 32
#define NEG_SLOPE 0.2f
#define BN_SCALE 0.9999950000374997f   // 1/sqrt(1+1e-5)
#define NB_SCAN 391                    // ceil(NN/256)
#define MPAD 100096                    // NN padded to multiple of 128

using half8 = __attribute__((ext_vector_type(8))) _Float16;
using f32x4 = __attribute__((ext_vector_type(4))) float;

typedef const __attribute__((address_space(1))) void* gas_ptr;
typedef __attribute__((address_space(3))) void* las_ptr;

// ---------------------------------------------------------------------------
// Tiled MFMA GEMM: C[m][n] = sum_k A[m][k] * Wt[n][k]
//   A fp16 [M][K] row-major (M padded to >= grid*128 rows, garbage pad ok)
//   Wt fp16 [NOUT][K] row-major (weights pre-transposed)
//   C fp16 [M][NOUT] (padded; pad rows receive garbage, never read)
// Tile: BM=128 x BN=(128 or 64), BK=64. 4 waves in 2x2; each wave owns
// 64 x (BN/2) output = MIxNI 16x16 fragments.
// LDS: double-buffered A[128][64] + B[BN][64] fp16, linear dest via
// global_load_lds(16B), XOR-swizzled SOURCE (unit ^= row&7) and the same
// XOR applied on ds_read_b128 -> 2-way banks (free) instead of 16-way.
// One barrier per K-step, stage-ahead prefetch (m97 2-phase structure).
// MODE 1: + bias[col], ReLU.
// ATT 1 (requires BN=128): fused attention-score epilogue. Each wave covers
// 64 rows x 64 cols = one full head -> a_s[row][head] = sum_c acc*as_[col]
// computed from f32 accumulators (4 fma/(mi,r)/array + 16-lane shfl reduce),
// no atomics: each (row,head) is owned by exactly one wave. Replaces the
// att_score kernel and its full 51MB xh re-read per layer.
// ---------------------------------------------------------------------------
template<int K, int NOUT, int MODE, int ATT>
__global__ __launch_bounds__(256, 2) void mgemm2(const __half* __restrict__ A,
                                                 const __half* __restrict__ Wt,
                                                 const float* __restrict__ bias,
                                                 __half* __restrict__ C,
                                                 const float* __restrict__ as_,
                                                 const float* __restrict__ ad_,
                                                 float* __restrict__ a_s,
                                                 float* __restrict__ a_d) {
    constexpr int BM = 128;
    constexpr int BN = (NOUT >= 128) ? 128 : 64;
    constexpr int MI = 4;
    constexpr int NI = BN / 32;
    constexpr int KS = K / 64;
    constexpr int ABYTES = BM * 128;   // 128 rows x 64 halfs
    constexpr int BBYTES = BN * 128;
    __shared__ char smem[2 * (ABYTES + BBYTES)];

    const int tid  = threadIdx.x;
    const int wave = tid >> 6, lane = tid & 63;
    const int wr = wave >> 1, wc = wave & 1;
    const int lrow = lane & 15, kq = lane >> 4;
    const int m0 = blockIdx.x * BM;
    const int n0 = blockIdx.y * BN;
    const int srow = tid >> 3;         // 0..31 staging row within 32-row slab
    const int sunit = tid & 7;         // physical 16B unit within row
    const int wofs = (tid & 192) * 16; // wave-uniform LDS offset (w*1024)

    // stage one BK=64 tile of A and B into buffer `buf`
    auto stage = [&](int buf, int ks) {
        char* base = smem + buf * (ABYTES + BBYTES);
        const int kk = ks * 64;
#pragma unroll
        for (int it = 0; it < BM / 32; ++it) {
            const int r = srow + it * 32;
            const __half* src = A + (size_t)(m0 + r) * K + kk + ((sunit ^ (r & 7)) << 3);
            __builtin_amdgcn_global_load_lds((gas_ptr)src,
                (las_ptr)(base + it * 4096 + wofs), 16, 0, 0);
        }
#pragma unroll
        for (int it = 0; it < BN / 32; ++it) {
            const int r = srow + it * 32;
            const __half* src = Wt + (size_t)(n0 + r) * K + kk + ((sunit ^ (r & 7)) << 3);
            __builtin_amdgcn_global_load_lds((gas_ptr)src,
                (las_ptr)(base + ABYTES + it * 4096 + wofs), 16, 0, 0);
        }
    };

    f32x4 acc[MI][NI] = {};

    auto compute = [&](int buf) {
        const char* Ab = smem + buf * (ABYTES + BBYTES);
        const char* Bb = Ab + ABYTES;
#pragma unroll
        for (int k32 = 0; k32 < 2; ++k32) {
            const int ku = k32 * 4 + kq;       // logical 16B unit (0..7)
            half8 af[MI], bf[NI];
#pragma unroll
            for (int mi = 0; mi < MI; ++mi) {
                const int rr = wr * 64 + mi * 16 + lrow;
                af[mi] = *(const half8*)(Ab + rr * 128 + ((ku ^ (rr & 7)) << 4));
            }
#pragma unroll
            for (int ni = 0; ni < NI; ++ni) {
                const int rc = wc * (BN / 2) + ni * 16 + lrow;
                bf[ni] = *(const half8*)(Bb + rc * 128 + ((ku ^ (rc & 7)) << 4));
            }
#pragma unroll
            for (int mi = 0; mi < MI; ++mi)
#pragma unroll
                for (int ni = 0; ni < NI; ++ni)
                    acc[mi][ni] = __builtin_amdgcn_mfma_f32_16x16x32_f16(
                        af[mi], bf[ni], acc[mi][ni], 0, 0, 0);
        }
    };

    stage(0, 0);
    __syncthreads();                    // drain prologue stage
    int cur = 0;
#pragma unroll
    for (int ks = 0; ks < KS; ++ks) {
        if (ks + 1 < KS) stage(cur ^ 1, ks + 1);
        compute(cur);
        __syncthreads();                // drains next stage + guards re-stage
        cur ^= 1;
    }

    const int crow = kq * 4;
#pragma unroll
    for (int mi = 0; mi < MI; ++mi) {
#pragma unroll
        for (int ni = 0; ni < NI; ++ni) {
            const int col = n0 + wc * (BN / 2) + ni * 16 + lrow;
            float bcol = (MODE == 1) ? bias[col] : 0.f;
#pragma unroll
            for (int r = 0; r < 4; ++r) {
                float v = acc[mi][ni][r];
                if constexpr (MODE == 1) v = fmaxf(v + bcol, 0.f);
                const int row = m0 + wr * 64 + mi * 16 + crow + r;
                C[(size_t)row * NOUT + col] = __float2half(v);
            }
        }
    }

    if constexpr (ATT) {
        // wave covers one head's full 64 cols -> complete dot in-wave
        const int head = (n0 + wc * 64) >> 6;
        float wsv[NI], wdv[NI];
#pragma unroll
        for (int ni = 0; ni < NI; ++ni) {
            const int col = n0 + wc * (BN / 2) + ni * 16 + lrow;
            wsv[ni] = as_[col];
            wdv[ni] = ad_[col];
        }
#pragma unroll
        for (int mi = 0; mi < MI; ++mi) {
#pragma unroll
            for (int r = 0; r < 4; ++r) {
                float ss = 0.f, dd = 0.f;
#pragma unroll
                for (int ni = 0; ni < NI; ++ni) {
                    ss += acc[mi][ni][r] * wsv[ni];
                    dd += acc[mi][ni][r] * wdv[ni];
                }
#pragma unroll
                for (int off = 8; off >= 1; off >>= 1) {
                    ss += __shfl_xor(ss, off, 64);
                    dd += __shfl_xor(dd, off, 64);
                }
                if (lrow == 0) {
                    const int row = m0 + wr * 64 + mi * 16 + crow + r;
                    a_s[row * HEADS + head] = ss;
                    a_d[row * HEADS + head] = dd;
                }
            }
        }
    }
}

// ---------------------------------------------------------------------------
// Prep kernels: transpose-convert weights to fp16 NxK, cast x to fp16.
// ---------------------------------------------------------------------------
__global__ __launch_bounds__(256) void wt_conv(const float* __restrict__ W,
                                               __half* __restrict__ Wt,
                                               int K, int N) {
    int idx = blockIdx.x * 256 + threadIdx.x;   // over N*K, output-contiguous
    if (idx >= K * N) return;
    int n = idx / K, k = idx % K;
    Wt[idx] = __float2half(W[k * N + n]);
}

// Wt_final[n][k]: n<32 -> W1[k][n] (W1s), n>=32 -> W1[256+k][n-32] (W1d)
__global__ __launch_bounds__(256) void wt_final(const float* __restrict__ W1,
                                                __half* __restrict__ Wt) {
    int idx = blockIdx.x * 256 + threadIdx.x;   // over 64*256
    if (idx >= 64 * 256) return;
    int n = idx >> 8, k = idx & 255;
    float v = (n < 32) ? W1[k * 32 + n] : W1[(256 + k) * 32 + (n - 32)];
    Wt[idx] = __float2half(v);
}

__global__ __launch_bounds__(256) void cvt_x(const float* __restrict__ x,
                                             __half* __restrict__ x16) {
    int i = blockIdx.x * 256 + threadIdx.x;     // over NN*F_NODE/4
    float4 v = ((const float4*)x)[i];
    __half2* o = (__half2*)x16 + (size_t)i * 2;
    o[0] = __floats2half2_rn(v.x, v.y);
    o[1] = __floats2half2_rn(v.z, v.w);
}

// ---------------------------------------------------------------------------
// CSR build: deg-count, two-level exclusive scan, scatter.
// ---------------------------------------------------------------------------
__global__ __launch_bounds__(256) void csr_count(const int* __restrict__ dst,
                                                 int* __restrict__ deg,
                                                 int* __restrict__ pos) {
    int e = blockIdx.x * 256 + threadIdx.x;
    if (e >= EE) return;
    pos[e] = atomicAdd(deg + dst[e], 1);
}

__device__ __forceinline__ int wave_incl_scan(int v, int lane) {
#pragma unroll
    for (int off = 1; off < 64; off <<= 1) {
        int t = __shfl_up(v, off, 64);
        if (lane >= off) v += t;
    }
    return v;
}

__global__ __launch_bounds__(256) void scan1(const int* __restrict__ deg,
                                             int* __restrict__ rowptr,
                                             int* __restrict__ bsum) {
    int tid = threadIdx.x, n = blockIdx.x * 256 + tid;
    int lane = tid & 63, wave = tid >> 6;
    int d = (n < NN) ? deg[n] : 0;
    int v = wave_incl_scan(d, lane);
    __shared__ int ws[4];
    if (lane == 63) ws[wave] = v;
    __syncthreads();
    int woff = 0;
    for (int w = 0; w < wave; ++w) woff += ws[w];
    int incl = v + woff;
    if (n < NN) rowptr[n] = incl - d;
    if (tid == 255) bsum[blockIdx.x] = incl;
}

__global__ __launch_bounds__(512) void scan2(const int* __restrict__ bsum,
                                             int* __restrict__ boff) {
    int t = threadIdx.x;
    int lane = t & 63, wave = t >> 6;
    int d = (t < NB_SCAN) ? bsum[t] : 0;
    int v = wave_incl_scan(d, lane);
    __shared__ int ws[8];
    if (lane == 63) ws[wave] = v;
    __syncthreads();
    int woff = 0;
    for (int w = 0; w < wave; ++w) woff += ws[w];
    if (t < NB_SCAN) boff[t] = v + woff - d;
}

__global__ __launch_bounds__(256) void scan3(int* __restrict__ rowptr,
                                             const int* __restrict__ boff) {
    int n = blockIdx.x * 256 + threadIdx.x;
    if (n == 0) rowptr[NN] = EE;
    if (n < NN) rowptr[n] += boff[blockIdx.x];
}

__global__ __launch_bounds__(256) void csr_scatter(const int* __restrict__ src,
                                                   const int* __restrict__ dst,
                                                   const int* __restrict__ rowptr,
                                                   const int* __restrict__ pos,
                                                   int* __restrict__ srcs) {
    int e = blockIdx.x * 256 + threadIdx.x;
    if (e >= EE) return;
    srcs[rowptr[dst[e]] + pos[e]] = src[e];
}

// ---------------------------------------------------------------------------
// Gather-aggregate with FUSED edge scoring + BN/ReLU/residual.
// One wave per dst node; each HALF-wave (32 lanes) owns one edge slot with
// 16B half8 loads -> one load instr fetches 2 rows; x4 unroll per half =
// 8 rows in flight per wave. Score ex = exp(lrelu(a_s[src]+a_d[n])) computed
// inline (a_s is 1.6MB -> L2-resident gather); no exs/perm round-trip.
// ---------------------------------------------------------------------------
__global__ __launch_bounds__(256) void gather_agg(const int* __restrict__ rowptr,
                                                  const int* __restrict__ srcs,
                                                  const float* __restrict__ a_s,
                                                  const float* __restrict__ a_d,
                                                  const __half* __restrict__ xh,
                                                  const float* __restrict__ bg,
                                                  const float* __restrict__ g,
                                                  const float* __restrict__ be,
                                                  __half* __restrict__ h,
                                                  int residual) {
    const int n = blockIdx.x * 4 + (threadIdx.x >> 6);
    const int lane = threadIdx.x & 63;
    if (n >= NN) return;
    const int hl = lane >> 5;          // half-wave: edge-slot parity
    const int l5 = lane & 31;
    const int hd = l5 >> 3;            // head of my 8 cols
    const int c0 = l5 * 8;             // col base (16B aligned)

    const int start = rowptr[n], end = rowptr[n + 1];
    const float adv = a_d[n * HEADS + hd];

    float acc[8] = {};
    float den = 0.f;

    for (int i = start + hl; i < end; i += 8) {
        // 4 slots per half: i, i+2, i+4, i+6 (clamped; zero weight past end)
        int  j0 = i,                 j1 = (i + 2 < end) ? i + 2 : i;
        int  j2 = (i + 4 < end) ? i + 4 : i;
        int  j3 = (i + 6 < end) ? i + 6 : i;
        const int s0 = srcs[j0], s1 = srcs[j1], s2 = srcs[j2], s3 = srcs[j3];

        float v0 = a_s[s0 * HEADS + hd] + adv;
        float v1 = a_s[s1 * HEADS + hd] + adv;
        float v2 = a_s[s2 * HEADS + hd] + adv;
        float v3 = a_s[s3 * HEADS + hd] + adv;
        v0 = fmaxf(v0, v0 * NEG_SLOPE);
        v1 = fmaxf(v1, v1 * NEG_SLOPE);
        v2 = fmaxf(v2, v2 * NEG_SLOPE);
        v3 = fmaxf(v3, v3 * NEG_SLOPE);
        float e0 = __expf(v0);
        float e1 = (i + 2 < end) ? __expf(v1) : 0.f;
        float e2 = (i + 4 < end) ? __expf(v2) : 0.f;
        float e3 = (i + 6 < end) ? __expf(v3) : 0.f;

        half8 r0 = *(const half8*)(xh + (size_t)s0 * HC + c0);
        half8 r1 = *(const half8*)(xh + (size_t)s1 * HC + c0);
        half8 r2 = *(const half8*)(xh + (size_t)s2 * HC + c0);
        half8 r3 = *(const half8*)(xh + (size_t)s3 * HC + c0);

#pragma unroll
        for (int k = 0; k < 8; ++k)
            acc[k] += e0 * (float)r0[k] + e1 * (float)r1[k]
                    + e2 * (float)r2[k] + e3 * (float)r3[k];
        den += e0 + e1 + e2 + e3;
    }

    // combine the two half-waves (same node, disjoint edge subsets)
    den += __shfl_xor(den, 32, 64);
#pragma unroll
    for (int k = 0; k < 8; ++k) acc[k] += __shfl_xor(acc[k], 32, 64);

    if (hl != 0) return;               // half 0 holds full sums; writes row
    const float inv = 1.f / (den + 1e-16f);

    float bgv[8], gv[8], bev[8];
    *(float4*)(bgv)     = *(const float4*)(bg + c0);
    *(float4*)(bgv + 4) = *(const float4*)(bg + c0 + 4);
    *(float4*)(gv)      = *(const float4*)(g + c0);
    *(float4*)(gv + 4)  = *(const float4*)(g + c0 + 4);
    *(float4*)(bev)     = *(const float4*)(be + c0);
    *(float4*)(bev + 4) = *(const float4*)(be + c0 + 4);

    half8* hp = (half8*)(h + (size_t)n * HC + c0);
    float r[8];
#pragma unroll
    for (int k = 0; k < 8; ++k)
        r[k] = fmaxf((acc[k] * inv + bgv[k]) * (gv[k] * BN_SCALE) + bev[k], 0.f);
    if (residual) {
        half8 old = *hp;
#pragma unroll
        for (int k = 0; k < 8; ++k) r[k] += (float)old[k];
    }
    half8 o;
#pragma unroll
    for (int k = 0; k < 8; ++k) o[k] = (_Float16)r[k];
    __builtin_nontemporal_store(o, hp);   // don't let h-stream evict xh
}

// ---------------------------------------------------------------------------
// Final fused edge MLP:
// Phase 1: per block, 64 edges; MFMA computes z_pre = ea@W1e + b1 into LDS.
// Phase 2: 4 threads/edge gather hs[src], hd[dst], ReLU, dot(W2), reduce.
// ---------------------------------------------------------------------------
__global__ __launch_bounds__(256) void edge_final(const float* __restrict__ ea,
                                                  const __half* __restrict__ w1et,
                                                  const float* __restrict__ b1,
                                                  const int* __restrict__ src,
                                                  const int* __restrict__ dst,
                                                  const __half* __restrict__ hshd,
                                                  const float* __restrict__ W2,
                                                  const float* __restrict__ b2,
                                                  float* __restrict__ out) {
    __shared__ float zl[64][36];   // stride 36: 16B-aligned rows, <=2-way banks
    const int wave = threadIdx.x >> 6, lane = threadIdx.x & 63;
    const int e0 = blockIdx.x * 64;
    const int lrow = lane & 15, kofs = (lane >> 4) * 8;

    // ---- Phase 1: MFMA z = ea @ W1e (K=32), 16 edges per wave ----
    int er = e0 + wave * 16 + lrow;
    if (er >= EE) er = EE - 1;
    const float* ap = ea + (size_t)er * F_EDGE + kofs;
    float4 f0 = *(const float4*)ap;
    float4 f1 = *(const float4*)(ap + 4);
    half8 a;
    a[0] = (_Float16)f0.x; a[1] = (_Float16)f0.y;
    a[2] = (_Float16)f0.z; a[3] = (_Float16)f0.w;
    a[4] = (_Float16)f1.x; a[5] = (_Float16)f1.y;
    a[6] = (_Float16)f1.z; a[7] = (_Float16)f1.w;

    half8 b0 = *(const half8*)(w1et + (size_t)lrow * 32 + kofs);
    half8 b1v = *(const half8*)(w1et + (size_t)(16 + lrow) * 32 + kofs);
    f32x4 acc0 = {}, acc1 = {};
    acc0 = __builtin_amdgcn_mfma_f32_16x16x32_f16(a, b0,  acc0, 0, 0, 0);
    acc1 = __builtin_amdgcn_mfma_f32_16x16x32_f16(a, b1v, acc1, 0, 0, 0);

    const int crow = (lane >> 4) * 4;
    const float bc0 = b1[lrow], bc1 = b1[16 + lrow];
#pragma unroll
    for (int r = 0; r < 4; ++r) {
        zl[wave * 16 + crow + r][lrow]      = acc0[r] + bc0;
        zl[wave * 16 + crow + r][16 + lrow] = acc1[r] + bc1;
    }
    __syncthreads();

    // ---- Phase 2: gather + ReLU + dot(W2) ----
    const int el = threadIdx.x >> 2, j0 = (threadIdx.x & 3) * 8;
    const int e = e0 + el;
    const bool ok = e < EE;
    const int s = ok ? src[e] : 0;
    const int d = ok ? dst[e] : 0;

    half8 hs = *(const half8*)(hshd + (size_t)s * 64 + j0);
    half8 hdv = *(const half8*)(hshd + (size_t)d * 64 + 32 + j0);
    float w2v[8];
    *(float4*)(w2v)     = *(const float4*)(W2 + j0);
    *(float4*)(w2v + 4) = *(const float4*)(W2 + j0 + 4);
    float4 z0 = *(const float4*)&zl[el][j0];
    float4 z1 = *(const float4*)&zl[el][j0 + 4];

    float acc = 0.f;
    const float* zp0 = &z0.x;
    const float* zp1 = &z1.x;
#pragma unroll
    for (int i = 0; i < 4; ++i) {
        float z = zp0[i] + (float)hs[i] + (float)hdv[i];
        acc += fmaxf(z, 0.f) * w2v[i];
    }
#pragma unroll
    for (int i = 0; i < 4; ++i) {
        float z = zp1[i] + (float)hs[4 + i] + (float)hdv[4 + i];
        acc += fmaxf(z, 0.f) * w2v[4 + i];
    }
    acc += __shfl_xor(acc, 1, 64);
    acc += __shfl_xor(acc, 2, 64);
    if (ok && (threadIdx.x & 3) == 0) out[e] = acc + b2[0];
}

// ---------------------------------------------------------------------------
extern "C" void kernel_launch(void* const* d_in, const int* in_sizes, int n_in,
                              void* d_out, int out_size, void* d_ws, size_t ws_size,
                              hipStream_t stream) {
    const float* x  = (const float*)d_in[0];
    const int*   ei = (const int*)d_in[1];
    const float* ea = (const float*)d_in[2];
    const float* Wp = (const float*)d_in[3];
    const float* bp = (const float*)d_in[4];
    const float* W1 = (const float*)d_in[23];
    const float* b1 = (const float*)d_in[24];
    const float* W2 = (const float*)d_in[25];
    const float* b2 = (const float*)d_in[26];
    const int* src = ei;
    const int* dst = ei + EE;

    // Workspace layout (float offsets). All matrix buffers padded to MPAD
    // rows so the 782-block (128-row) GEMM grid needs no bounds checks.
    // a_s/a_d sized MPAD*HEADS (pad rows written by the ATT epilogue).
    float* ws = (float*)d_ws;
    __half* h      = (__half*)(ws);               // MPAD*256 halfs
    __half* xh     = (__half*)(ws + 12820000);    // MPAD*256 halfs
    __half* x16    = (__half*)(ws + 25640000);    // MPAD*128 halfs
    __half* h0     = (__half*)(ws + 32050000);    // MPAD*64 halfs
    __half* hshd   = (__half*)(ws + 35260000);    // MPAD*64 halfs
    float*  a_s    = ws + 38470000;               // MPAD*4 (410000 slot)
    float*  a_d    = ws + 38880000;               // MPAD*4
    int*    rowptr = (int*)(ws + 41270000);       // NN+1
    int*    deg    = (int*)(ws + 41380000);       // NN
    int*    pos    = (int*)(ws + 41480000);       // EE
    int*    srcs   = (int*)(ws + 42490000);       // EE
    int*    bsum   = (int*)(ws + 42990000);       // NB_SCAN
    int*    boff   = (int*)(ws + 42991000);       // NB_SCAN
    __half* wpt    = (__half*)(ws + 42992000);    // 64x128 (reused as w1et)
    __half* wgt    = (__half*)(ws + 43000000);    // 256x256
    __half* w1t    = (__half*)(ws + 43020000);    // 64x256
    float*  out    = (float*)d_out;

    const int MB = MPAD / 128;   // 782 row-blocks

    // ---- CSR build (once) ----
    hipMemsetAsync(deg, 0, (size_t)NN * sizeof(int), stream);
    csr_count<<<(EE + 255) / 256, 256, 0, stream>>>(dst, deg, pos);
    scan1<<<NB_SCAN, 256, 0, stream>>>(deg, rowptr, bsum);
    scan2<<<1, 512, 0, stream>>>(bsum, boff);
    scan3<<<NB_SCAN, 256, 0, stream>>>(rowptr, boff);
    csr_scatter<<<(EE + 255) / 256, 256, 0, stream>>>(src, dst, rowptr, pos, srcs);

    // ---- prep: x->fp16, Wp^T ----
    cvt_x<<<NN * F_NODE / 4 / 256, 256, 0, stream>>>(x, x16);
    wt_conv<<<(F_NODE * 64 + 255) / 256, 256, 0, stream>>>(Wp, wpt, F_NODE, 64);

    // h0 = relu(x @ Wp + bp)
    mgemm2<F_NODE, 64, 1, 0><<<dim3(MB, 1), 256, 0, stream>>>(
        x16, wpt, bp, h0, nullptr, nullptr, nullptr, nullptr);

    for (int l = 0; l < 3; ++l) {
        const float* Wg  = (const float*)d_in[5 + 6 * l];
        const float* as_ = (const float*)d_in[6 + 6 * l];
        const float* ad_ = (const float*)d_in[7 + 6 * l];
        const float* bg  = (const float*)d_in[8 + 6 * l];
        const float* g   = (const float*)d_in[9 + 6 * l];
        const float* be  = (const float*)d_in[10 + 6 * l];

        if (l == 0) {
            wt_conv<<<(CC * HC + 255) / 256, 256, 0, stream>>>(Wg, wgt, CC, HC);
            mgemm2<CC, HC, 0, 1><<<dim3(MB, 2), 256, 0, stream>>>(
                h0, wgt, nullptr, xh, as_, ad_, a_s, a_d);
        } else {
            wt_conv<<<(HC * HC + 255) / 256, 256, 0, stream>>>(Wg, wgt, HC, HC);
            mgemm2<HC, HC, 0, 1><<<dim3(MB, 2), 256, 0, stream>>>(
                h, wgt, nullptr, xh, as_, ad_, a_s, a_d);
        }

        gather_agg<<<(NN + 3) / 4, 256, 0, stream>>>(rowptr, srcs, a_s, a_d, xh,
                                                     bg, g, be, h, l > 0 ? 1 : 0);
    }

    // hs|hd = h @ [W1s | W1d]
    wt_final<<<(64 * 256 + 255) / 256, 256, 0, stream>>>(W1, w1t);
    mgemm2<HC, 64, 0, 0><<<dim3(MB, 1), 256, 0, stream>>>(
        h, w1t, nullptr, hshd, nullptr, nullptr, nullptr, nullptr);

    // W1e^T -> fp16 (reuse wpt; first mgemm2 that used it is long done)
    wt_conv<<<(32 * 32 + 255) / 256, 256, 0, stream>>>(W1 + 2 * HC * OUTD, wpt, 32, 32);
    edge_final<<<(EE + 63) / 64, 256, 0, stream>>>(ea, wpt, b1, src, dst, hshd, W2, b2, out);
}